// Round 7
// baseline (250.353 us; speedup 1.0000x reference)
//
#include <hip/hip_runtime.h>
#include <hip/hip_fp16.h>
#include <math.h>

#define N_NODES 10000
#define E_EDGES 160000
#define DMODEL 64
#define H 4
#define NBOUND 31
// qall record per node (fp16, 1024 halves):
//  [0:256)    h  d-major: offset d*4 + head   (one 8B load = all 4 heads at d)
//  [256:512)  q1: 256 + head*64 + d
//  [512:768)  q2: 512 + head*64 + d
//  [768:1024) q3: 768 + head*64 + d
#define QREC 1024

typedef _Float16 half8 __attribute__((ext_vector_type(8)));
typedef float floatx4 __attribute__((ext_vector_type(4)));

// ---------------------------------------------------------------------------
// A: merged prep (pos4 pack + counts zero) and pre1 (B[kh] = fck @ F -> Bws).
// Blocks 0..11: pre1 (kh = bi). Blocks 12..51: prep over nodes.
// ---------------------------------------------------------------------------
__global__ __launch_bounds__(256) void prep_pre1_kernel(
    const float* __restrict__ fc1, const float* __restrict__ fc2,
    const float* __restrict__ fc3, const float* __restrict__ fcc,
    float* __restrict__ Bws, const float* __restrict__ pos,
    float4* __restrict__ pos4, int* __restrict__ counts) {
  __shared__ __align__(16) float S[12288];  // [0:8192) fck, [8192:12288) F
  int bi = blockIdx.x;
  int tid = threadIdx.x;
  if (bi >= 12) {
    int n = (bi - 12) * 256 + tid;
    if (n < N_NODES) {
      counts[n] = 0;
      pos4[n] = make_float4(pos[n * 3], pos[n * 3 + 1], pos[n * 3 + 2], 0.f);
    }
    return;
  }
  int kh = bi;
  int k = kh >> 2, h = kh & 3;
  const float* fck = (k == 0) ? fc1 : (k == 1) ? fc2 : fc3;
  fck += h * 128 * 64;
  const float* F = fcc + h * 192 * 64 + k * 64 * 64;
  #pragma unroll
  for (int u = 0; u < 8; ++u)
    ((float4*)S)[u * 256 + tid] = ((const float4*)fck)[u * 256 + tid];
  #pragma unroll
  for (int u = 0; u < 4; ++u)
    ((float4*)(S + 8192))[u * 256 + tid] = ((const float4*)F)[u * 256 + tid];
  __syncthreads();
  int j = tid & 63, ig = tid >> 6;
  #pragma unroll
  for (int rg = 0; rg < 8; ++rg) {
    int i0 = ig * 32 + rg * 4;
    float a0 = 0.f, a1 = 0.f, a2 = 0.f, a3 = 0.f;
    #pragma unroll
    for (int t4 = 0; t4 < 16; ++t4) {
      float4 f0 = *(const float4*)&S[(i0 + 0) * 64 + t4 * 4];
      float4 f1 = *(const float4*)&S[(i0 + 1) * 64 + t4 * 4];
      float4 f2 = *(const float4*)&S[(i0 + 2) * 64 + t4 * 4];
      float4 f3 = *(const float4*)&S[(i0 + 3) * 64 + t4 * 4];
      float b0 = S[8192 + (t4 * 4 + 0) * 64 + j];
      float b1 = S[8192 + (t4 * 4 + 1) * 64 + j];
      float b2 = S[8192 + (t4 * 4 + 2) * 64 + j];
      float b3 = S[8192 + (t4 * 4 + 3) * 64 + j];
      a0 += f0.x * b0 + f0.y * b1 + f0.z * b2 + f0.w * b3;
      a1 += f1.x * b0 + f1.y * b1 + f1.z * b2 + f1.w * b3;
      a2 += f2.x * b0 + f2.y * b1 + f2.z * b2 + f2.w * b3;
      a3 += f3.x * b0 + f3.y * b1 + f3.z * b2 + f3.w * b3;
    }
    Bws[kh * 8192 + (i0 + 0) * 64 + j] = a0;
    Bws[kh * 8192 + (i0 + 1) * 64 + j] = a1;
    Bws[kh * 8192 + (i0 + 2) * 64 + j] = a2;
    Bws[kh * 8192 + (i0 + 3) * 64 + j] = a3;
  }
}

// ---------------------------------------------------------------------------
// CSR: count + scan
// ---------------------------------------------------------------------------
__global__ __launch_bounds__(256) void count_kernel(const int* __restrict__ dst,
                                                    int* __restrict__ counts) {
  int e = blockIdx.x * 256 + threadIdx.x;
  if (e < E_EDGES) atomicAdd(&counts[dst[e]], 1);
}

__global__ __launch_bounds__(1024) void scan_kernel(const int* __restrict__ counts,
                                                    int* __restrict__ starts,
                                                    int* __restrict__ cursor) {
  __shared__ int lds[1024];
  int tid = threadIdx.x;
  int base = tid * 10;
  int loc[10];
  int s = 0;
  #pragma unroll
  for (int u = 0; u < 10; ++u) {
    int i = base + u;
    int v = (i < N_NODES) ? counts[i] : 0;
    loc[u] = s;
    s += v;
  }
  lds[tid] = s;
  __syncthreads();
  int inc = s;
  for (int off = 1; off < 1024; off <<= 1) {
    int y = (tid >= off) ? lds[tid - off] : 0;
    __syncthreads();
    inc += y;
    lds[tid] = inc;
    __syncthreads();
  }
  int excl = inc - s;
  #pragma unroll
  for (int u = 0; u < 10; ++u) {
    int i = base + u;
    if (i < N_NODES) {
      int v = excl + loc[u];
      starts[i] = v;
      cursor[i] = v;
    }
  }
  if (tid == 1023) starts[N_NODES] = inc;
}

// ---------------------------------------------------------------------------
// B: merged fill (CSR scatter, also records esrc) and pre2.
// Blocks 0..59: pre2 (kh = bi/5, role = bi%5). Blocks 60..684: fill.
// ---------------------------------------------------------------------------
__global__ __launch_bounds__(256) void fill_pre2_kernel(
    const float* __restrict__ Wfc, const float* __restrict__ G,
    const float* __restrict__ emb, const float* __restrict__ Bws,
    __half* __restrict__ bigWT, __half* __restrict__ U16,
    const int* __restrict__ dst, const int* __restrict__ src,
    int* __restrict__ cursor, int* __restrict__ elist,
    int* __restrict__ esrc) {
  __shared__ __align__(16) float S[9216];
  int bi = blockIdx.x;
  int tid = threadIdx.x;
  if (bi >= 60) {
    int e = (bi - 60) * 256 + tid;
    if (e < E_EDGES) {
      int p = atomicAdd(&cursor[dst[e]], 1);
      elist[p] = e;
      esrc[p] = src[e];
    }
    return;
  }
  int kh = bi / 5, role = bi % 5;
  int k = kh >> 2, h = kh & 3;
  int j = tid & 63;
  if (role < 4) {
    int r0 = role * 32;
    #pragma unroll
    for (int u = 0; u < 4; ++u)
      ((float4*)S)[u * 256 + tid] = ((const float4*)(Bws + kh * 8192))[u * 256 + tid];
    #pragma unroll
    for (int u = 0; u < 2; ++u) {
      int fi = u * 256 + tid;
      int i = fi >> 4, c4 = fi & 15;
      ((float4*)(S + 4096))[fi] =
          ((const float4*)(Wfc + (r0 + i) * 256 + h * 64))[c4];
    }
    __syncthreads();
    int ig = tid >> 6;
    int i0 = ig * 8;
    #pragma unroll
    for (int g4 = 0; g4 < 2; ++g4) {
      int ib = i0 + g4 * 4;
      float a0 = 0.f, a1 = 0.f, a2 = 0.f, a3 = 0.f;
      #pragma unroll
      for (int t4 = 0; t4 < 16; ++t4) {
        float4 f0 = *(const float4*)&S[4096 + (ib + 0) * 64 + t4 * 4];
        float4 f1 = *(const float4*)&S[4096 + (ib + 1) * 64 + t4 * 4];
        float4 f2 = *(const float4*)&S[4096 + (ib + 2) * 64 + t4 * 4];
        float4 f3 = *(const float4*)&S[4096 + (ib + 3) * 64 + t4 * 4];
        float b0 = S[(t4 * 4 + 0) * 64 + j];
        float b1 = S[(t4 * 4 + 1) * 64 + j];
        float b2 = S[(t4 * 4 + 2) * 64 + j];
        float b3 = S[(t4 * 4 + 3) * 64 + j];
        a0 += f0.x * b0 + f0.y * b1 + f0.z * b2 + f0.w * b3;
        a1 += f1.x * b0 + f1.y * b1 + f1.z * b2 + f1.w * b3;
        a2 += f2.x * b0 + f2.y * b1 + f2.z * b2 + f2.w * b3;
        a3 += f3.x * b0 + f3.y * b1 + f3.z * b2 + f3.w * b3;
      }
      __half hv[4] = {__float2half(a0), __float2half(a1), __float2half(a2),
                      __float2half(a3)};
      *(uint2*)&bigWT[((k + 1) * 256 + h * 64 + j) * 128 + r0 + ib] =
          *(uint2*)hv;
    }
    if (k == 0) {
      #pragma unroll
      for (int u = 0; u < 8; ++u) {
        int idx = u * 256 + tid;
        int i = idx >> 6, jj = idx & 63;
        bigWT[(h * 64 + jj) * 128 + r0 + i] = __float2half(S[4096 + idx]);
      }
    }
  } else {
    // [0:4096) B2, [4096:6144) G, [6144:7168) emb, [7168:9216) GB
    #pragma unroll
    for (int u = 0; u < 4; ++u)
      ((float4*)S)[u * 256 + tid] =
          ((const float4*)(Bws + kh * 8192 + 4096))[u * 256 + tid];
    #pragma unroll
    for (int u = 0; u < 2; ++u)
      ((float4*)(S + 4096))[u * 256 + tid] =
          ((const float4*)(G + h * 2048))[u * 256 + tid];
    ((float4*)(S + 6144))[tid] = ((const float4*)emb)[tid];
    __syncthreads();
    int wv = tid >> 6;
    #pragma unroll
    for (int rg = 0; rg < 2; ++rg) {
      int g0 = wv * 8 + rg * 4;
      float a0 = 0.f, a1 = 0.f, a2 = 0.f, a3 = 0.f;
      #pragma unroll
      for (int t4 = 0; t4 < 16; ++t4) {
        float4 f0 = *(const float4*)&S[4096 + (g0 + 0) * 64 + t4 * 4];
        float4 f1 = *(const float4*)&S[4096 + (g0 + 1) * 64 + t4 * 4];
        float4 f2 = *(const float4*)&S[4096 + (g0 + 2) * 64 + t4 * 4];
        float4 f3 = *(const float4*)&S[4096 + (g0 + 3) * 64 + t4 * 4];
        float b0 = S[(t4 * 4 + 0) * 64 + j];
        float b1 = S[(t4 * 4 + 1) * 64 + j];
        float b2 = S[(t4 * 4 + 2) * 64 + j];
        float b3 = S[(t4 * 4 + 3) * 64 + j];
        a0 += f0.x * b0 + f0.y * b1 + f0.z * b2 + f0.w * b3;
        a1 += f1.x * b0 + f1.y * b1 + f1.z * b2 + f1.w * b3;
        a2 += f2.x * b0 + f2.y * b1 + f2.z * b2 + f2.w * b3;
        a3 += f3.x * b0 + f3.y * b1 + f3.z * b2 + f3.w * b3;
      }
      S[7168 + (g0 + 0) * 64 + j] = a0;
      S[7168 + (g0 + 1) * 64 + j] = a1;
      S[7168 + (g0 + 2) * 64 + j] = a2;
      S[7168 + (g0 + 3) * 64 + j] = a3;
    }
    __syncthreads();
    #pragma unroll
    for (int rg = 0; rg < 2; ++rg) {
      int e0 = wv * 8 + rg * 4;
      float a0 = 0.f, a1 = 0.f, a2 = 0.f, a3 = 0.f;
      #pragma unroll
      for (int t4 = 0; t4 < 8; ++t4) {
        float4 f0 = *(const float4*)&S[6144 + (e0 + 0) * 32 + t4 * 4];
        float4 f1 = *(const float4*)&S[6144 + (e0 + 1) * 32 + t4 * 4];
        float4 f2 = *(const float4*)&S[6144 + (e0 + 2) * 32 + t4 * 4];
        float4 f3 = *(const float4*)&S[6144 + (e0 + 3) * 32 + t4 * 4];
        float b0 = S[7168 + (t4 * 4 + 0) * 64 + j];
        float b1 = S[7168 + (t4 * 4 + 1) * 64 + j];
        float b2 = S[7168 + (t4 * 4 + 2) * 64 + j];
        float b3 = S[7168 + (t4 * 4 + 3) * 64 + j];
        a0 += f0.x * b0 + f0.y * b1 + f0.z * b2 + f0.w * b3;
        a1 += f1.x * b0 + f1.y * b1 + f1.z * b2 + f1.w * b3;
        a2 += f2.x * b0 + f2.y * b1 + f2.z * b2 + f2.w * b3;
        a3 += f3.x * b0 + f3.y * b1 + f3.z * b2 + f3.w * b3;
      }
      int base = k * 8192 + h * 2048;
      U16[base + (e0 + 0) * 64 + j] = __float2half(a0);
      U16[base + (e0 + 1) * 64 + j] = __float2half(a1);
      U16[base + (e0 + 2) * 64 + j] = __float2half(a2);
      U16[base + (e0 + 3) * 64 + j] = __float2half(a3);
    }
  }
}

// ---------------------------------------------------------------------------
// K1: qall(fp16) = feat(fp32) @ bigWT^T via MFMA 16x16x32 f16.
// Epilogue: region 0 (h) stored d-major [d*4+head]; regions 1-3 plain.
// ---------------------------------------------------------------------------
__global__ __launch_bounds__(256) void gemm_kernel(
    const float* __restrict__ feat, const __half* __restrict__ bigWT,
    __half* __restrict__ qall) {
  int tid = threadIdx.x;
  int wv = tid >> 6, l = tid & 63;
  int m0 = blockIdx.x * 64 + wv * 16;
  int n0 = blockIdx.y * 64;
  int lm = l & 15, lk = (l >> 4) * 8;
  int arow = m0 + lm;
  if (arow >= N_NODES) arow = N_NODES - 1;
  const float* fp = feat + arow * 128 + lk;
  const _Float16* bp = (const _Float16*)bigWT + lk;
  floatx4 acc[4];
  #pragma unroll
  for (int nt = 0; nt < 4; ++nt) acc[nt] = (floatx4){0.f, 0.f, 0.f, 0.f};
  #pragma unroll
  for (int kt = 0; kt < 4; ++kt) {
    float4 f0 = *(const float4*)(fp + kt * 32);
    float4 f1 = *(const float4*)(fp + kt * 32 + 4);
    half8 a;
    a[0] = (_Float16)f0.x; a[1] = (_Float16)f0.y;
    a[2] = (_Float16)f0.z; a[3] = (_Float16)f0.w;
    a[4] = (_Float16)f1.x; a[5] = (_Float16)f1.y;
    a[6] = (_Float16)f1.z; a[7] = (_Float16)f1.w;
    #pragma unroll
    for (int nt = 0; nt < 4; ++nt) {
      half8 b = *(const half8*)(bp + (n0 + nt * 16 + lm) * 128 + kt * 32);
      acc[nt] = __builtin_amdgcn_mfma_f32_16x16x32_f16(a, b, acc[nt], 0, 0, 0);
    }
  }
  int reg = n0 >> 8;             // 0=h,1=q1,2=q2,3=q3 (block-uniform)
  int hh = (n0 & 255) >> 6;      // head (block-uniform)
  int mrow = m0 + (l >> 4) * 4;
  #pragma unroll
  for (int nt = 0; nt < 4; ++nt) {
    #pragma unroll
    for (int r4 = 0; r4 < 4; ++r4) {
      int m = mrow + r4;
      if (m < N_NODES) {
        int dd = nt * 16 + lm;
        int off = (reg == 0) ? (dd * 4 + hh) : (reg * 256 + hh * 64 + dd);
        qall[m * QREC + off] = __float2half(acc[nt][r4]);
      }
    }
  }
}

// ---------------------------------------------------------------------------
// K3: edge-parallel SCORE kernel in CSR order. One wave per CSR slot i.
// lane layout: h = lane>>4, c = lane&15 (4 halves each). Max-free softmax
// (|score| <= ~15 -> exp cannot overflow fp32). Writes exsc[i*4+h].
// ---------------------------------------------------------------------------
__device__ __forceinline__ int didx(const float* __restrict__ bnd2, float d) {
  int g = (int)(d * 10.0f);
  g = (g < 0) ? 0 : ((g > 31) ? 31 : g);
  g += (bnd2[g + 1] < d) ? 1 : 0;
  g -= (bnd2[g] >= d) ? 1 : 0;
  return g;
}

__device__ __forceinline__ float fast_tanh(float z) {
  float a = fabsf(z);
  float p = __expf(2.0f * a);
  float r = 1.0f - 2.0f / (p + 1.0f);
  return copysignf(r, z);
}

__device__ __forceinline__ float dpp_row_sum16(float v) {
  int x;
  x = __builtin_amdgcn_update_dpp(0, __float_as_int(v), 0x128, 0xf, 0xf, true);
  v += __int_as_float(x);
  x = __builtin_amdgcn_update_dpp(0, __float_as_int(v), 0x124, 0xf, 0xf, true);
  v += __int_as_float(x);
  x = __builtin_amdgcn_update_dpp(0, __float_as_int(v), 0x122, 0xf, 0xf, true);
  v += __int_as_float(x);
  x = __builtin_amdgcn_update_dpp(0, __float_as_int(v), 0x121, 0xf, 0xf, true);
  v += __int_as_float(x);
  return v;
}

__device__ __forceinline__ float4 h4_to_f4(uint2 u) {
  union { uint2 ui; __half2 h[2]; } cc;
  cc.ui = u;
  float2 a = __half22float2(cc.h[0]);
  float2 b = __half22float2(cc.h[1]);
  return make_float4(a.x, a.y, b.x, b.y);
}

__global__ __launch_bounds__(256) void score_kernel(
    const int* __restrict__ elist, const int* __restrict__ src,
    const int* __restrict__ dst, const int* __restrict__ inter,
    const float4* __restrict__ pos4, const float* __restrict__ boundaries,
    const __half* __restrict__ qall, const __half* __restrict__ U16,
    const float* __restrict__ aout, float* __restrict__ exsc) {
  __shared__ float bnd2[33];
  int tid = threadIdx.x;
  if (tid < NBOUND) bnd2[tid + 1] = boundaries[tid];
  if (tid == NBOUND) { bnd2[0] = -INFINITY; bnd2[32] = INFINITY; }
  __syncthreads();
  int wv = tid >> 6, lane = tid & 63;
  int h = lane >> 4, c = lane & 15;
  int i = blockIdx.x * 4 + wv;  // CSR slot; grid*4 == E exactly
  int e = elist[i];
  int s = src[e], t = dst[e];
  int it = inter[e * H + h];
  float4 ps = pos4[s], pt = pos4[t], pi = pos4[it];
  float dx = pt.x - ps.x, dy = pt.y - ps.y, dz = pt.z - ps.z;
  float dist1 = sqrtf(dx * dx + dy * dy + dz * dz);
  float ax = pt.x - pi.x, ay = pt.y - pi.y, az = pt.z - pi.z;
  float dist2 = sqrtf(ax * ax + ay * ay + az * az);
  float bx = ps.x - pi.x, by = ps.y - pi.y, bz = ps.z - pi.z;
  float dist_ = sqrtf(bx * bx + by * by + bz * bz);
  int idx1 = didx(bnd2, dist1);
  int idx2 = didx(bnd2, dist2);
  int idx_ = didx(bnd2, dist_);
  const float4 A = h4_to_f4(*(const uint2*)(qall + s * QREC + 256 + h * 64 + c * 4));
  const float4 B = h4_to_f4(*(const uint2*)(qall + it * QREC + 512 + h * 64 + c * 4));
  const float4 C = h4_to_f4(*(const uint2*)(qall + t * QREC + 768 + h * 64 + c * 4));
  const float4 X = h4_to_f4(*(const uint2*)(U16 + (h * 32 + idx1) * 64 + c * 4));
  const float4 Y = h4_to_f4(*(const uint2*)(U16 + 8192 + (h * 32 + idx2) * 64 + c * 4));
  const float4 Z = h4_to_f4(*(const uint2*)(U16 + 16384 + (h * 32 + idx_) * 64 + c * 4));
  const float4 a4 = *((const float4*)(aout + h * 64) + c);
  float t0 = fast_tanh(A.x + B.x + C.x + X.x + Y.x + Z.x);
  float t1 = fast_tanh(A.y + B.y + C.y + X.y + Y.y + Z.y);
  float t2 = fast_tanh(A.z + B.z + C.z + X.z + Y.z + Z.z);
  float t3 = fast_tanh(A.w + B.w + C.w + X.w + Y.w + Z.w);
  float v = t0 * a4.x + t1 * a4.y + t2 * a4.z + t3 * a4.w;
  v = dpp_row_sum16(v);
  if (c == 0) exsc[i * 4 + h] = __expf(v);
}

// ---------------------------------------------------------------------------
// K4: aggregation. Block per dst node; 4 waves stride CSR slots; lane = d.
// Per slot: ex4 (16B seq) + esrc (4B seq) + one 8B d-major h gather + 4 FMA.
// ---------------------------------------------------------------------------
__global__ __launch_bounds__(256) void agg_kernel(
    const int* __restrict__ starts, const int* __restrict__ esrc,
    const float* __restrict__ exsc, const __half* __restrict__ qall,
    float* __restrict__ out) {
  __shared__ float4 sm_num[4][64];
  __shared__ float4 sm_den[4];
  int tid = threadIdx.x;
  int w = tid >> 6, lane = tid & 63;
  int n = blockIdx.x;
  int b = starts[n], e_end = starts[n + 1];
  float4 num = make_float4(0.f, 0.f, 0.f, 0.f);
  float4 den = make_float4(0.f, 0.f, 0.f, 0.f);
  int i = b + w;
  float4 ex4 = make_float4(0.f, 0.f, 0.f, 0.f);
  uint2 hraw = {0, 0};
  if (i < e_end) {
    ex4 = *(const float4*)(exsc + i * 4);
    int s = esrc[i];
    hraw = *(const uint2*)(qall + s * QREC + lane * 4);
  }
  while (i < e_end) {
    int inext = i + 4;
    float4 ex4n = make_float4(0.f, 0.f, 0.f, 0.f);
    uint2 hrawn = {0, 0};
    if (inext < e_end) {
      ex4n = *(const float4*)(exsc + inext * 4);
      int sn = esrc[inext];
      hrawn = *(const uint2*)(qall + sn * QREC + lane * 4);
    }
    float4 hv = h4_to_f4(hraw);  // h[d=lane][head 0..3]
    num.x += ex4.x * hv.x;
    num.y += ex4.y * hv.y;
    num.z += ex4.z * hv.z;
    num.w += ex4.w * hv.w;
    den.x += ex4.x; den.y += ex4.y; den.z += ex4.z; den.w += ex4.w;
    i = inext;
    ex4 = ex4n;
    hraw = hrawn;
  }
  sm_num[w][lane] = num;
  if (lane == 0) sm_den[w] = den;
  __syncthreads();
  if (tid < 64) {
    float4 n0 = sm_num[0][tid], n1 = sm_num[1][tid];
    float4 n2 = sm_num[2][tid], n3 = sm_num[3][tid];
    float4 d0 = sm_den[0], d1 = sm_den[1], d2 = sm_den[2], d3 = sm_den[3];
    float4 ns = make_float4(n0.x + n1.x + n2.x + n3.x, n0.y + n1.y + n2.y + n3.y,
                            n0.z + n1.z + n2.z + n3.z, n0.w + n1.w + n2.w + n3.w);
    float4 ds = make_float4(d0.x + d1.x + d2.x + d3.x, d0.y + d1.y + d2.y + d3.y,
                            d0.z + d1.z + d2.z + d3.z, d0.w + d1.w + d2.w + d3.w);
    float r = 0.f;
    if (e_end > b)
      r = 0.25f * (ns.x / ds.x + ns.y / ds.y + ns.z / ds.z + ns.w / ds.w);
    out[n * 64 + tid] = r;
  }
}

// ---------------------------------------------------------------------------
extern "C" void kernel_launch(void* const* d_in, const int* in_sizes, int n_in,
                              void* d_out, int out_size, void* d_ws,
                              size_t ws_size, hipStream_t stream) {
  const float* feat = (const float*)d_in[0];
  const float* loc = (const float*)d_in[1];
  const int* src = (const int*)d_in[2];
  const int* dst = (const int*)d_in[3];
  const int* inter = (const int*)d_in[4];
  const float* Wfc = (const float*)d_in[5];
  const float* emb = (const float*)d_in[6];
  const float* G = (const float*)d_in[7];
  const float* fc1 = (const float*)d_in[8];
  const float* fc2 = (const float*)d_in[9];
  const float* fc3 = (const float*)d_in[10];
  const float* fcc = (const float*)d_in[11];
  const float* aout = (const float*)d_in[12];
  const float* bnd = (const float*)d_in[13];
  float* out = (float*)d_out;

  __half* qall = (__half*)d_ws;                    // N*1024 halfs (20.48 MB)
  __half* bigWT = qall + N_NODES * QREC;           // 1024*128 halfs
  __half* U16 = bigWT + 1024 * 128;                // 3*4*2048 halfs
  float* Bws = (float*)(U16 + 3 * H * 2048);       // 12*8192 f32
  float4* pos4 = (float4*)(Bws + 12 * 8192);       // N float4
  float* exsc = (float*)(pos4 + N_NODES);          // E*4 f32 (2.56 MB)
  int* counts = (int*)(exsc + E_EDGES * 4);        // N
  int* starts = counts + N_NODES;                  // N+1
  int* cursor = starts + N_NODES + 1;              // N
  int* elist = cursor + N_NODES;                   // E
  int* esrc = elist + E_EDGES;                     // E

  prep_pre1_kernel<<<52, 256, 0, stream>>>(fc1, fc2, fc3, fcc, Bws, loc, pos4,
                                           counts);
  count_kernel<<<(E_EDGES + 255) / 256, 256, 0, stream>>>(dst, counts);
  scan_kernel<<<1, 1024, 0, stream>>>(counts, starts, cursor);
  fill_pre2_kernel<<<60 + (E_EDGES + 255) / 256, 256, 0, stream>>>(
      Wfc, G, emb, Bws, bigWT, U16, dst, src, cursor, elist, esrc);
  dim3 ggrid((N_NODES + 63) / 64, 16);
  gemm_kernel<<<ggrid, 256, 0, stream>>>(feat, bigWT, qall);
  score_kernel<<<E_EDGES / 4, 256, 0, stream>>>(elist, src, dst, inter, pos4,
                                                bnd, qall, U16, aout, exsc);
  agg_kernel<<<N_NODES, 256, 0, stream>>>(starts, esrc, exsc, qall, out);
}

// Round 8
// 229.352 us; speedup vs baseline: 1.0916x; 1.0916x over previous
//
#include <hip/hip_runtime.h>
#include <hip/hip_fp16.h>
#include <math.h>

#define N_NODES 10000
#define E_EDGES 160000
#define DMODEL 64
#define H 4
#define NBOUND 31
// qall record per node (fp16, 1024 halves):
//  [0:256)    h  d-major: offset d*4 + head   (one 8B load = all 4 heads at d)
//  [256:512)  q1: 256 + head*64 + d
//  [512:768)  q2: 512 + head*64 + d
//  [768:1024) q3: 768 + head*64 + d
#define QREC 1024

typedef _Float16 half8 __attribute__((ext_vector_type(8)));
typedef float floatx4 __attribute__((ext_vector_type(4)));

// ---------------------------------------------------------------------------
// D1: merged prep (pos4 pack + counts zero) and pre1 (B[kh] = fck @ F -> Bws).
// Blocks 0..11: pre1. Blocks 12..51: prep over nodes.
// ---------------------------------------------------------------------------
__global__ __launch_bounds__(256) void prep_pre1_kernel(
    const float* __restrict__ fc1, const float* __restrict__ fc2,
    const float* __restrict__ fc3, const float* __restrict__ fcc,
    float* __restrict__ Bws, const float* __restrict__ pos,
    float4* __restrict__ pos4, int* __restrict__ counts) {
  __shared__ __align__(16) float S[12288];  // [0:8192) fck, [8192:12288) F
  int bi = blockIdx.x;
  int tid = threadIdx.x;
  if (bi >= 12) {
    int n = (bi - 12) * 256 + tid;
    if (n < N_NODES) {
      counts[n] = 0;
      pos4[n] = make_float4(pos[n * 3], pos[n * 3 + 1], pos[n * 3 + 2], 0.f);
    }
    return;
  }
  int kh = bi;
  int k = kh >> 2, h = kh & 3;
  const float* fck = (k == 0) ? fc1 : (k == 1) ? fc2 : fc3;
  fck += h * 128 * 64;
  const float* F = fcc + h * 192 * 64 + k * 64 * 64;
  #pragma unroll
  for (int u = 0; u < 8; ++u)
    ((float4*)S)[u * 256 + tid] = ((const float4*)fck)[u * 256 + tid];
  #pragma unroll
  for (int u = 0; u < 4; ++u)
    ((float4*)(S + 8192))[u * 256 + tid] = ((const float4*)F)[u * 256 + tid];
  __syncthreads();
  int j = tid & 63, ig = tid >> 6;
  #pragma unroll
  for (int rg = 0; rg < 8; ++rg) {
    int i0 = ig * 32 + rg * 4;
    float a0 = 0.f, a1 = 0.f, a2 = 0.f, a3 = 0.f;
    #pragma unroll
    for (int t4 = 0; t4 < 16; ++t4) {
      float4 f0 = *(const float4*)&S[(i0 + 0) * 64 + t4 * 4];
      float4 f1 = *(const float4*)&S[(i0 + 1) * 64 + t4 * 4];
      float4 f2 = *(const float4*)&S[(i0 + 2) * 64 + t4 * 4];
      float4 f3 = *(const float4*)&S[(i0 + 3) * 64 + t4 * 4];
      float b0 = S[8192 + (t4 * 4 + 0) * 64 + j];
      float b1 = S[8192 + (t4 * 4 + 1) * 64 + j];
      float b2 = S[8192 + (t4 * 4 + 2) * 64 + j];
      float b3 = S[8192 + (t4 * 4 + 3) * 64 + j];
      a0 += f0.x * b0 + f0.y * b1 + f0.z * b2 + f0.w * b3;
      a1 += f1.x * b0 + f1.y * b1 + f1.z * b2 + f1.w * b3;
      a2 += f2.x * b0 + f2.y * b1 + f2.z * b2 + f2.w * b3;
      a3 += f3.x * b0 + f3.y * b1 + f3.z * b2 + f3.w * b3;
    }
    Bws[kh * 8192 + (i0 + 0) * 64 + j] = a0;
    Bws[kh * 8192 + (i0 + 1) * 64 + j] = a1;
    Bws[kh * 8192 + (i0 + 2) * 64 + j] = a2;
    Bws[kh * 8192 + (i0 + 3) * 64 + j] = a3;
  }
}

// ---------------------------------------------------------------------------
// searchsorted-left over boundaries (exact, LDS table with +-inf pads)
// ---------------------------------------------------------------------------
__device__ __forceinline__ int didx(const float* __restrict__ bnd2, float d) {
  int g = (int)(d * 10.0f);
  g = (g < 0) ? 0 : ((g > 31) ? 31 : g);
  g += (bnd2[g + 1] < d) ? 1 : 0;
  g -= (bnd2[g] >= d) ? 1 : 0;
  return g;
}

// ---------------------------------------------------------------------------
// D2: merged pre2 (blocks 0..59) and dist/count (blocks 60..2559).
// dist path: one lane per (e,h): 3 dists -> packed didx indices widx[e*4+h];
// lane h==0 also does the dst-count atomic (replaces count_kernel).
// ---------------------------------------------------------------------------
__global__ __launch_bounds__(256) void pre2_dist_kernel(
    const float* __restrict__ Wfc, const float* __restrict__ G,
    const float* __restrict__ emb, const float* __restrict__ Bws,
    __half* __restrict__ bigWT, __half* __restrict__ U16,
    const int* __restrict__ src, const int* __restrict__ dst,
    const int* __restrict__ inter, const float4* __restrict__ pos4,
    const float* __restrict__ boundaries, int* __restrict__ counts,
    int* __restrict__ widx) {
  __shared__ __align__(16) float S[9216];
  int bi = blockIdx.x;
  int tid = threadIdx.x;
  if (bi >= 60) {
    // dist/count path; bnd2 aliases S[0:33]
    if (tid < NBOUND) S[tid + 1] = boundaries[tid];
    if (tid == NBOUND) { S[0] = -INFINITY; S[32] = INFINITY; }
    __syncthreads();
    int g = (bi - 60) * 256 + tid;  // (e,h); 2500 blocks x 256 == E*4 exactly
    int e = g >> 2, h = g & 3;
    int s = src[e], t = dst[e];
    int it = inter[g];  // e*4+h == g
    float4 ps = pos4[s], pt = pos4[t], pi = pos4[it];
    float dx = pt.x - ps.x, dy = pt.y - ps.y, dz = pt.z - ps.z;
    float dist1 = sqrtf(dx * dx + dy * dy + dz * dz);
    float ax = pt.x - pi.x, ay = pt.y - pi.y, az = pt.z - pi.z;
    float dist2 = sqrtf(ax * ax + ay * ay + az * az);
    float bx = ps.x - pi.x, by = ps.y - pi.y, bz = ps.z - pi.z;
    float dist_ = sqrtf(bx * bx + by * by + bz * bz);
    int idx1 = didx(S, dist1);
    int idx2 = didx(S, dist2);
    int idx_ = didx(S, dist_);
    widx[g] = idx1 | (idx2 << 5) | (idx_ << 10);
    if (h == 0) atomicAdd(&counts[t], 1);
    return;
  }
  int kh = bi / 5, role = bi % 5;
  int k = kh >> 2, h = kh & 3;
  int j = tid & 63;
  if (role < 4) {
    int r0 = role * 32;
    #pragma unroll
    for (int u = 0; u < 4; ++u)
      ((float4*)S)[u * 256 + tid] = ((const float4*)(Bws + kh * 8192))[u * 256 + tid];
    #pragma unroll
    for (int u = 0; u < 2; ++u) {
      int fi = u * 256 + tid;
      int i = fi >> 4, c4 = fi & 15;
      ((float4*)(S + 4096))[fi] =
          ((const float4*)(Wfc + (r0 + i) * 256 + h * 64))[c4];
    }
    __syncthreads();
    int ig = tid >> 6;
    int i0 = ig * 8;
    #pragma unroll
    for (int g4 = 0; g4 < 2; ++g4) {
      int ib = i0 + g4 * 4;
      float a0 = 0.f, a1 = 0.f, a2 = 0.f, a3 = 0.f;
      #pragma unroll
      for (int t4 = 0; t4 < 16; ++t4) {
        float4 f0 = *(const float4*)&S[4096 + (ib + 0) * 64 + t4 * 4];
        float4 f1 = *(const float4*)&S[4096 + (ib + 1) * 64 + t4 * 4];
        float4 f2 = *(const float4*)&S[4096 + (ib + 2) * 64 + t4 * 4];
        float4 f3 = *(const float4*)&S[4096 + (ib + 3) * 64 + t4 * 4];
        float b0 = S[(t4 * 4 + 0) * 64 + j];
        float b1 = S[(t4 * 4 + 1) * 64 + j];
        float b2 = S[(t4 * 4 + 2) * 64 + j];
        float b3 = S[(t4 * 4 + 3) * 64 + j];
        a0 += f0.x * b0 + f0.y * b1 + f0.z * b2 + f0.w * b3;
        a1 += f1.x * b0 + f1.y * b1 + f1.z * b2 + f1.w * b3;
        a2 += f2.x * b0 + f2.y * b1 + f2.z * b2 + f2.w * b3;
        a3 += f3.x * b0 + f3.y * b1 + f3.z * b2 + f3.w * b3;
      }
      __half hv[4] = {__float2half(a0), __float2half(a1), __float2half(a2),
                      __float2half(a3)};
      *(uint2*)&bigWT[((k + 1) * 256 + h * 64 + j) * 128 + r0 + ib] =
          *(uint2*)hv;
    }
    if (k == 0) {
      #pragma unroll
      for (int u = 0; u < 8; ++u) {
        int idx = u * 256 + tid;
        int i = idx >> 6, jj = idx & 63;
        bigWT[(h * 64 + jj) * 128 + r0 + i] = __float2half(S[4096 + idx]);
      }
    }
  } else {
    // [0:4096) B2, [4096:6144) G, [6144:7168) emb, [7168:9216) GB
    #pragma unroll
    for (int u = 0; u < 4; ++u)
      ((float4*)S)[u * 256 + tid] =
          ((const float4*)(Bws + kh * 8192 + 4096))[u * 256 + tid];
    #pragma unroll
    for (int u = 0; u < 2; ++u)
      ((float4*)(S + 4096))[u * 256 + tid] =
          ((const float4*)(G + h * 2048))[u * 256 + tid];
    ((float4*)(S + 6144))[tid] = ((const float4*)emb)[tid];
    __syncthreads();
    int wv = tid >> 6;
    #pragma unroll
    for (int rg = 0; rg < 2; ++rg) {
      int g0 = wv * 8 + rg * 4;
      float a0 = 0.f, a1 = 0.f, a2 = 0.f, a3 = 0.f;
      #pragma unroll
      for (int t4 = 0; t4 < 16; ++t4) {
        float4 f0 = *(const float4*)&S[4096 + (g0 + 0) * 64 + t4 * 4];
        float4 f1 = *(const float4*)&S[4096 + (g0 + 1) * 64 + t4 * 4];
        float4 f2 = *(const float4*)&S[4096 + (g0 + 2) * 64 + t4 * 4];
        float4 f3 = *(const float4*)&S[4096 + (g0 + 3) * 64 + t4 * 4];
        float b0 = S[(t4 * 4 + 0) * 64 + j];
        float b1 = S[(t4 * 4 + 1) * 64 + j];
        float b2 = S[(t4 * 4 + 2) * 64 + j];
        float b3 = S[(t4 * 4 + 3) * 64 + j];
        a0 += f0.x * b0 + f0.y * b1 + f0.z * b2 + f0.w * b3;
        a1 += f1.x * b0 + f1.y * b1 + f1.z * b2 + f1.w * b3;
        a2 += f2.x * b0 + f2.y * b1 + f2.z * b2 + f2.w * b3;
        a3 += f3.x * b0 + f3.y * b1 + f3.z * b2 + f3.w * b3;
      }
      S[7168 + (g0 + 0) * 64 + j] = a0;
      S[7168 + (g0 + 1) * 64 + j] = a1;
      S[7168 + (g0 + 2) * 64 + j] = a2;
      S[7168 + (g0 + 3) * 64 + j] = a3;
    }
    __syncthreads();
    #pragma unroll
    for (int rg = 0; rg < 2; ++rg) {
      int e0 = wv * 8 + rg * 4;
      float a0 = 0.f, a1 = 0.f, a2 = 0.f, a3 = 0.f;
      #pragma unroll
      for (int t4 = 0; t4 < 8; ++t4) {
        float4 f0 = *(const float4*)&S[6144 + (e0 + 0) * 32 + t4 * 4];
        float4 f1 = *(const float4*)&S[6144 + (e0 + 1) * 32 + t4 * 4];
        float4 f2 = *(const float4*)&S[6144 + (e0 + 2) * 32 + t4 * 4];
        float4 f3 = *(const float4*)&S[6144 + (e0 + 3) * 32 + t4 * 4];
        float b0 = S[7168 + (t4 * 4 + 0) * 64 + j];
        float b1 = S[7168 + (t4 * 4 + 1) * 64 + j];
        float b2 = S[7168 + (t4 * 4 + 2) * 64 + j];
        float b3 = S[7168 + (t4 * 4 + 3) * 64 + j];
        a0 += f0.x * b0 + f0.y * b1 + f0.z * b2 + f0.w * b3;
        a1 += f1.x * b0 + f1.y * b1 + f1.z * b2 + f1.w * b3;
        a2 += f2.x * b0 + f2.y * b1 + f2.z * b2 + f2.w * b3;
        a3 += f3.x * b0 + f3.y * b1 + f3.z * b2 + f3.w * b3;
      }
      int base = k * 8192 + h * 2048;
      U16[base + (e0 + 0) * 64 + j] = __float2half(a0);
      U16[base + (e0 + 1) * 64 + j] = __float2half(a1);
      U16[base + (e0 + 2) * 64 + j] = __float2half(a2);
      U16[base + (e0 + 3) * 64 + j] = __float2half(a3);
    }
  }
}

// ---------------------------------------------------------------------------
// D3: scan
// ---------------------------------------------------------------------------
__global__ __launch_bounds__(1024) void scan_kernel(const int* __restrict__ counts,
                                                    int* __restrict__ starts,
                                                    int* __restrict__ cursor) {
  __shared__ int lds[1024];
  int tid = threadIdx.x;
  int base = tid * 10;
  int loc[10];
  int s = 0;
  #pragma unroll
  for (int u = 0; u < 10; ++u) {
    int i = base + u;
    int v = (i < N_NODES) ? counts[i] : 0;
    loc[u] = s;
    s += v;
  }
  lds[tid] = s;
  __syncthreads();
  int inc = s;
  for (int off = 1; off < 1024; off <<= 1) {
    int y = (tid >= off) ? lds[tid - off] : 0;
    __syncthreads();
    inc += y;
    lds[tid] = inc;
    __syncthreads();
  }
  int excl = inc - s;
  #pragma unroll
  for (int u = 0; u < 10; ++u) {
    int i = base + u;
    if (i < N_NODES) {
      int v = excl + loc[u];
      starts[i] = v;
      cursor[i] = v;
    }
  }
  if (tid == 1023) starts[N_NODES] = inc;
}

// ---------------------------------------------------------------------------
// D4: merged fill (blocks 0..624) + MFMA gemm (blocks 625..3136).
// gemm: qall(fp16) = feat(fp32) @ bigWT^T via MFMA 16x16x32 f16.
// ---------------------------------------------------------------------------
__global__ __launch_bounds__(256) void fill_gemm_kernel(
    const int* __restrict__ dst, const int* __restrict__ src,
    int* __restrict__ cursor, int* __restrict__ elist, int* __restrict__ esrc,
    const float* __restrict__ feat, const __half* __restrict__ bigWT,
    __half* __restrict__ qall) {
  int bi = blockIdx.x;
  int tid = threadIdx.x;
  if (bi < 625) {
    int e = bi * 256 + tid;
    if (e < E_EDGES) {
      int p = atomicAdd(&cursor[dst[e]], 1);
      elist[p] = e;
      esrc[p] = src[e];
    }
    return;
  }
  int gb = bi - 625;            // 0..2511
  int bx = gb % 157, by = gb / 157;
  int wv = tid >> 6, l = tid & 63;
  int m0 = bx * 64 + wv * 16;
  int n0 = by * 64;
  int lm = l & 15, lk = (l >> 4) * 8;
  int arow = m0 + lm;
  if (arow >= N_NODES) arow = N_NODES - 1;
  const float* fp = feat + arow * 128 + lk;
  const _Float16* bp = (const _Float16*)bigWT + lk;
  floatx4 acc[4];
  #pragma unroll
  for (int nt = 0; nt < 4; ++nt) acc[nt] = (floatx4){0.f, 0.f, 0.f, 0.f};
  #pragma unroll
  for (int kt = 0; kt < 4; ++kt) {
    float4 f0 = *(const float4*)(fp + kt * 32);
    float4 f1 = *(const float4*)(fp + kt * 32 + 4);
    half8 a;
    a[0] = (_Float16)f0.x; a[1] = (_Float16)f0.y;
    a[2] = (_Float16)f0.z; a[3] = (_Float16)f0.w;
    a[4] = (_Float16)f1.x; a[5] = (_Float16)f1.y;
    a[6] = (_Float16)f1.z; a[7] = (_Float16)f1.w;
    #pragma unroll
    for (int nt = 0; nt < 4; ++nt) {
      half8 b = *(const half8*)(bp + (n0 + nt * 16 + lm) * 128 + kt * 32);
      acc[nt] = __builtin_amdgcn_mfma_f32_16x16x32_f16(a, b, acc[nt], 0, 0, 0);
    }
  }
  int reg = n0 >> 8;             // 0=h,1=q1,2=q2,3=q3 (block-uniform)
  int hh = (n0 & 255) >> 6;      // head (block-uniform)
  int mrow = m0 + (l >> 4) * 4;
  #pragma unroll
  for (int nt = 0; nt < 4; ++nt) {
    #pragma unroll
    for (int r4 = 0; r4 < 4; ++r4) {
      int m = mrow + r4;
      if (m < N_NODES) {
        int dd = nt * 16 + lm;
        int off = (reg == 0) ? (dd * 4 + hh) : (reg * 256 + hh * 64 + dd);
        qall[m * QREC + off] = __float2half(acc[nt][r4]);
      }
    }
  }
}

// ---------------------------------------------------------------------------
// D5: SCORE. One wave per CSR slot; h = lane>>4, c = lane&15.
// Dist/didx already precomputed (widx). z-sum in packed fp16.
// Max-free softmax (|score| <= ~15).
// ---------------------------------------------------------------------------
__device__ __forceinline__ float fast_tanh(float z) {
  float a = fabsf(z);
  float p = __expf(2.0f * a);
  float r = 1.0f - 2.0f / (p + 1.0f);
  return copysignf(r, z);
}

__device__ __forceinline__ float dpp_row_sum16(float v) {
  int x;
  x = __builtin_amdgcn_update_dpp(0, __float_as_int(v), 0x128, 0xf, 0xf, true);
  v += __int_as_float(x);
  x = __builtin_amdgcn_update_dpp(0, __float_as_int(v), 0x124, 0xf, 0xf, true);
  v += __int_as_float(x);
  x = __builtin_amdgcn_update_dpp(0, __float_as_int(v), 0x122, 0xf, 0xf, true);
  v += __int_as_float(x);
  x = __builtin_amdgcn_update_dpp(0, __float_as_int(v), 0x121, 0xf, 0xf, true);
  v += __int_as_float(x);
  return v;
}

union H4u { uint2 u; __half2 h[2]; };

__global__ __launch_bounds__(256) void score_kernel(
    const int* __restrict__ elist, const int* __restrict__ src,
    const int* __restrict__ dst, const int* __restrict__ inter,
    const int* __restrict__ widx, const __half* __restrict__ qall,
    const __half* __restrict__ U16, const float* __restrict__ aout,
    float* __restrict__ exsc) {
  int tid = threadIdx.x;
  int wv = tid >> 6, lane = tid & 63;
  int h = lane >> 4, c = lane & 15;
  int i = blockIdx.x * 4 + wv;  // CSR slot; grid*4 == E exactly
  int e = elist[i];
  int s = src[e], t = dst[e];
  int it = inter[e * 4 + h];
  int wp = widx[e * 4 + h];
  int idx1 = wp & 31, idx2 = (wp >> 5) & 31, idx_ = (wp >> 10) & 31;
  H4u A, B, C, X, Y, Z;
  A.u = *(const uint2*)(qall + s * QREC + 256 + h * 64 + c * 4);
  B.u = *(const uint2*)(qall + it * QREC + 512 + h * 64 + c * 4);
  C.u = *(const uint2*)(qall + t * QREC + 768 + h * 64 + c * 4);
  X.u = *(const uint2*)(U16 + (h * 32 + idx1) * 64 + c * 4);
  Y.u = *(const uint2*)(U16 + 8192 + (h * 32 + idx2) * 64 + c * 4);
  Z.u = *(const uint2*)(U16 + 16384 + (h * 32 + idx_) * 64 + c * 4);
  const float4 a4 = *((const float4*)(aout + h * 64) + c);
  __half2 z0 = __hadd2(__hadd2(A.h[0], B.h[0]), __hadd2(C.h[0], X.h[0]));
  z0 = __hadd2(z0, __hadd2(Y.h[0], Z.h[0]));
  __half2 z1 = __hadd2(__hadd2(A.h[1], B.h[1]), __hadd2(C.h[1], X.h[1]));
  z1 = __hadd2(z1, __hadd2(Y.h[1], Z.h[1]));
  float2 f0 = __half22float2(z0);
  float2 f1 = __half22float2(z1);
  float t0 = fast_tanh(f0.x);
  float t1 = fast_tanh(f0.y);
  float t2 = fast_tanh(f1.x);
  float t3 = fast_tanh(f1.y);
  float v = t0 * a4.x + t1 * a4.y + t2 * a4.z + t3 * a4.w;
  v = dpp_row_sum16(v);
  if (c == 0) exsc[i * 4 + h] = __expf(v);
}

// ---------------------------------------------------------------------------
// D6: aggregation. Block per dst node; 4 waves stride CSR slots; lane = d.
// ---------------------------------------------------------------------------
__device__ __forceinline__ float4 h4_to_f4(uint2 u) {
  union { uint2 ui; __half2 h[2]; } cc;
  cc.ui = u;
  float2 a = __half22float2(cc.h[0]);
  float2 b = __half22float2(cc.h[1]);
  return make_float4(a.x, a.y, b.x, b.y);
}

__global__ __launch_bounds__(256) void agg_kernel(
    const int* __restrict__ starts, const int* __restrict__ esrc,
    const float* __restrict__ exsc, const __half* __restrict__ qall,
    float* __restrict__ out) {
  __shared__ float4 sm_num[4][64];
  __shared__ float4 sm_den[4];
  int tid = threadIdx.x;
  int w = tid >> 6, lane = tid & 63;
  int n = blockIdx.x;
  int b = starts[n], e_end = starts[n + 1];
  float4 num = make_float4(0.f, 0.f, 0.f, 0.f);
  float4 den = make_float4(0.f, 0.f, 0.f, 0.f);
  int i = b + w;
  float4 ex4 = make_float4(0.f, 0.f, 0.f, 0.f);
  uint2 hraw = {0, 0};
  if (i < e_end) {
    ex4 = *(const float4*)(exsc + i * 4);
    int s = esrc[i];
    hraw = *(const uint2*)(qall + s * QREC + lane * 4);
  }
  while (i < e_end) {
    int inext = i + 4;
    float4 ex4n = make_float4(0.f, 0.f, 0.f, 0.f);
    uint2 hrawn = {0, 0};
    if (inext < e_end) {
      ex4n = *(const float4*)(exsc + inext * 4);
      int sn = esrc[inext];
      hrawn = *(const uint2*)(qall + sn * QREC + lane * 4);
    }
    float4 hv = h4_to_f4(hraw);  // h[d=lane][head 0..3]
    num.x += ex4.x * hv.x;
    num.y += ex4.y * hv.y;
    num.z += ex4.z * hv.z;
    num.w += ex4.w * hv.w;
    den.x += ex4.x; den.y += ex4.y; den.z += ex4.z; den.w += ex4.w;
    i = inext;
    ex4 = ex4n;
    hraw = hrawn;
  }
  sm_num[w][lane] = num;
  if (lane == 0) sm_den[w] = den;
  __syncthreads();
  if (tid < 64) {
    float4 n0 = sm_num[0][tid], n1 = sm_num[1][tid];
    float4 n2 = sm_num[2][tid], n3 = sm_num[3][tid];
    float4 d0 = sm_den[0], d1 = sm_den[1], d2 = sm_den[2], d3 = sm_den[3];
    float4 ns = make_float4(n0.x + n1.x + n2.x + n3.x, n0.y + n1.y + n2.y + n3.y,
                            n0.z + n1.z + n2.z + n3.z, n0.w + n1.w + n2.w + n3.w);
    float4 ds = make_float4(d0.x + d1.x + d2.x + d3.x, d0.y + d1.y + d2.y + d3.y,
                            d0.z + d1.z + d2.z + d3.z, d0.w + d1.w + d2.w + d3.w);
    float r = 0.f;
    if (e_end > b)
      r = 0.25f * (ns.x / ds.x + ns.y / ds.y + ns.z / ds.z + ns.w / ds.w);
    out[n * 64 + tid] = r;
  }
}

// ---------------------------------------------------------------------------
extern "C" void kernel_launch(void* const* d_in, const int* in_sizes, int n_in,
                              void* d_out, int out_size, void* d_ws,
                              size_t ws_size, hipStream_t stream) {
  const float* feat = (const float*)d_in[0];
  const float* loc = (const float*)d_in[1];
  const int* src = (const int*)d_in[2];
  const int* dst = (const int*)d_in[3];
  const int* inter = (const int*)d_in[4];
  const float* Wfc = (const float*)d_in[5];
  const float* emb = (const float*)d_in[6];
  const float* G = (const float*)d_in[7];
  const float* fc1 = (const float*)d_in[8];
  const float* fc2 = (const float*)d_in[9];
  const float* fc3 = (const float*)d_in[10];
  const float* fcc = (const float*)d_in[11];
  const float* aout = (const float*)d_in[12];
  const float* bnd = (const float*)d_in[13];
  float* out = (float*)d_out;

  __half* qall = (__half*)d_ws;                    // N*1024 halfs (20.48 MB)
  __half* bigWT = qall + N_NODES * QREC;           // 1024*128 halfs
  __half* U16 = bigWT + 1024 * 128;                // 3*4*2048 halfs
  float* Bws = (float*)(U16 + 3 * H * 2048);       // 12*8192 f32
  float4* pos4 = (float4*)(Bws + 12 * 8192);       // N float4
  float* exsc = (float*)(pos4 + N_NODES);          // E*4 f32 (2.56 MB)
  int* widx = (int*)(exsc + E_EDGES * 4);          // E*4 ints (2.56 MB)
  int* counts = widx + E_EDGES * 4;                // N
  int* starts = counts + N_NODES;                  // N+1
  int* cursor = starts + N_NODES + 1;              // N
  int* elist = cursor + N_NODES;                   // E
  int* esrc = elist + E_EDGES;                     // E

  prep_pre1_kernel<<<52, 256, 0, stream>>>(fc1, fc2, fc3, fcc, Bws, loc, pos4,
                                           counts);
  pre2_dist_kernel<<<60 + E_EDGES * 4 / 256, 256, 0, stream>>>(
      Wfc, G, emb, Bws, bigWT, U16, src, dst, inter, pos4, bnd, counts, widx);
  scan_kernel<<<1, 1024, 0, stream>>>(counts, starts, cursor);
  fill_gemm_kernel<<<625 + 157 * 16, 256, 0, stream>>>(dst, src, cursor, elist,
                                                       esrc, feat, bigWT, qall);
  score_kernel<<<E_EDGES / 4, 256, 0, stream>>>(elist, src, dst, inter, widx,
                                                qall, U16, aout, exsc);
  agg_kernel<<<N_NODES, 256, 0, stream>>>(starts, esrc, exsc, qall, out);
}

// Round 9
// 219.466 us; speedup vs baseline: 1.1407x; 1.0450x over previous
//
#include <hip/hip_runtime.h>
#include <hip/hip_fp16.h>
#include <math.h>

#define N_NODES 10000
#define E_EDGES 160000
#define DMODEL 64
#define H 4
#define NBOUND 31
// qall record per node (fp16, 1024 halves):
//  [0:256)    h  d-major: offset d*4 + head   (one 8B load = all 4 heads at d)
//  [256:512)  q1: 256 + head*64 + d
//  [512:768)  q2: 512 + head*64 + d
//  [768:1024) q3: 768 + head*64 + d
#define QREC 1024

typedef _Float16 half8 __attribute__((ext_vector_type(8)));
typedef float floatx4 __attribute__((ext_vector_type(4)));

// ---------------------------------------------------------------------------
// D1: blocks 0..11 pre1 (B[kh] = fck @ F -> Bws); 12..51 prep (pos4+counts);
//     52..1301 cvt feat -> feat16.
// ---------------------------------------------------------------------------
__global__ __launch_bounds__(256) void prep_pre1_cvt_kernel(
    const float* __restrict__ fc1, const float* __restrict__ fc2,
    const float* __restrict__ fc3, const float* __restrict__ fcc,
    float* __restrict__ Bws, const float* __restrict__ pos,
    float4* __restrict__ pos4, int* __restrict__ counts,
    const float* __restrict__ feat, __half* __restrict__ feat16) {
  __shared__ __align__(16) float S[12288];  // [0:8192) fck, [8192:12288) F
  int bi = blockIdx.x;
  int tid = threadIdx.x;
  if (bi >= 52) {
    int t = (bi - 52) * 256 + tid;  // 1250*256 == N*128/4 exactly
    float4 v = *(const float4*)(feat + t * 4);
    union { uint2 u; __half2 h[2]; } st;
    st.h[0] = __floats2half2_rn(v.x, v.y);
    st.h[1] = __floats2half2_rn(v.z, v.w);
    *(uint2*)&feat16[t * 4] = st.u;
    return;
  }
  if (bi >= 12) {
    int n = (bi - 12) * 256 + tid;
    if (n < N_NODES) {
      counts[n] = 0;
      pos4[n] = make_float4(pos[n * 3], pos[n * 3 + 1], pos[n * 3 + 2], 0.f);
    }
    return;
  }
  int kh = bi;
  int k = kh >> 2, h = kh & 3;
  const float* fck = (k == 0) ? fc1 : (k == 1) ? fc2 : fc3;
  fck += h * 128 * 64;
  const float* F = fcc + h * 192 * 64 + k * 64 * 64;
  #pragma unroll
  for (int u = 0; u < 8; ++u)
    ((float4*)S)[u * 256 + tid] = ((const float4*)fck)[u * 256 + tid];
  #pragma unroll
  for (int u = 0; u < 4; ++u)
    ((float4*)(S + 8192))[u * 256 + tid] = ((const float4*)F)[u * 256 + tid];
  __syncthreads();
  int j = tid & 63, ig = tid >> 6;
  #pragma unroll
  for (int rg = 0; rg < 8; ++rg) {
    int i0 = ig * 32 + rg * 4;
    float a0 = 0.f, a1 = 0.f, a2 = 0.f, a3 = 0.f;
    #pragma unroll
    for (int t4 = 0; t4 < 16; ++t4) {
      float4 f0 = *(const float4*)&S[(i0 + 0) * 64 + t4 * 4];
      float4 f1 = *(const float4*)&S[(i0 + 1) * 64 + t4 * 4];
      float4 f2 = *(const float4*)&S[(i0 + 2) * 64 + t4 * 4];
      float4 f3 = *(const float4*)&S[(i0 + 3) * 64 + t4 * 4];
      float b0 = S[8192 + (t4 * 4 + 0) * 64 + j];
      float b1 = S[8192 + (t4 * 4 + 1) * 64 + j];
      float b2 = S[8192 + (t4 * 4 + 2) * 64 + j];
      float b3 = S[8192 + (t4 * 4 + 3) * 64 + j];
      a0 += f0.x * b0 + f0.y * b1 + f0.z * b2 + f0.w * b3;
      a1 += f1.x * b0 + f1.y * b1 + f1.z * b2 + f1.w * b3;
      a2 += f2.x * b0 + f2.y * b1 + f2.z * b2 + f2.w * b3;
      a3 += f3.x * b0 + f3.y * b1 + f3.z * b2 + f3.w * b3;
    }
    Bws[kh * 8192 + (i0 + 0) * 64 + j] = a0;
    Bws[kh * 8192 + (i0 + 1) * 64 + j] = a1;
    Bws[kh * 8192 + (i0 + 2) * 64 + j] = a2;
    Bws[kh * 8192 + (i0 + 3) * 64 + j] = a3;
  }
}

// ---------------------------------------------------------------------------
__device__ __forceinline__ int didx(const float* __restrict__ bnd2, float d) {
  int g = (int)(d * 10.0f);
  g = (g < 0) ? 0 : ((g > 31) ? 31 : g);
  g += (bnd2[g + 1] < d) ? 1 : 0;
  g -= (bnd2[g] >= d) ? 1 : 0;
  return g;
}

// ---------------------------------------------------------------------------
// D2: blocks 0..59 pre2 (WC->bigWT fp16, U->U16 fp16); 60.. dist/count.
// ---------------------------------------------------------------------------
__global__ __launch_bounds__(256) void pre2_dist_kernel(
    const float* __restrict__ Wfc, const float* __restrict__ G,
    const float* __restrict__ emb, const float* __restrict__ Bws,
    __half* __restrict__ bigWT, __half* __restrict__ U16,
    const int* __restrict__ src, const int* __restrict__ dst,
    const int* __restrict__ inter, const float4* __restrict__ pos4,
    const float* __restrict__ boundaries, int* __restrict__ counts,
    int* __restrict__ widx) {
  __shared__ __align__(16) float S[9216];
  int bi = blockIdx.x;
  int tid = threadIdx.x;
  if (bi >= 60) {
    if (tid < NBOUND) S[tid + 1] = boundaries[tid];
    if (tid == NBOUND) { S[0] = -INFINITY; S[32] = INFINITY; }
    __syncthreads();
    int g = (bi - 60) * 256 + tid;  // (e,h); 2500 blocks x 256 == E*4
    int e = g >> 2, h = g & 3;
    int s = src[e], t = dst[e];
    int it = inter[g];
    float4 ps = pos4[s], pt = pos4[t], pi = pos4[it];
    float dx = pt.x - ps.x, dy = pt.y - ps.y, dz = pt.z - ps.z;
    float dist1 = sqrtf(dx * dx + dy * dy + dz * dz);
    float ax = pt.x - pi.x, ay = pt.y - pi.y, az = pt.z - pi.z;
    float dist2 = sqrtf(ax * ax + ay * ay + az * az);
    float bx = ps.x - pi.x, by = ps.y - pi.y, bz = ps.z - pi.z;
    float dist_ = sqrtf(bx * bx + by * by + bz * bz);
    int idx1 = didx(S, dist1);
    int idx2 = didx(S, dist2);
    int idx_ = didx(S, dist_);
    widx[g] = idx1 | (idx2 << 5) | (idx_ << 10);
    if (h == 0) atomicAdd(&counts[t], 1);
    return;
  }
  int kh = bi / 5, role = bi % 5;
  int k = kh >> 2, h = kh & 3;
  int j = tid & 63;
  if (role < 4) {
    int r0 = role * 32;
    #pragma unroll
    for (int u = 0; u < 4; ++u)
      ((float4*)S)[u * 256 + tid] = ((const float4*)(Bws + kh * 8192))[u * 256 + tid];
    #pragma unroll
    for (int u = 0; u < 2; ++u) {
      int fi = u * 256 + tid;
      int i = fi >> 4, c4 = fi & 15;
      ((float4*)(S + 4096))[fi] =
          ((const float4*)(Wfc + (r0 + i) * 256 + h * 64))[c4];
    }
    __syncthreads();
    int ig = tid >> 6;
    int i0 = ig * 8;
    #pragma unroll
    for (int g4 = 0; g4 < 2; ++g4) {
      int ib = i0 + g4 * 4;
      float a0 = 0.f, a1 = 0.f, a2 = 0.f, a3 = 0.f;
      #pragma unroll
      for (int t4 = 0; t4 < 16; ++t4) {
        float4 f0 = *(const float4*)&S[4096 + (ib + 0) * 64 + t4 * 4];
        float4 f1 = *(const float4*)&S[4096 + (ib + 1) * 64 + t4 * 4];
        float4 f2 = *(const float4*)&S[4096 + (ib + 2) * 64 + t4 * 4];
        float4 f3 = *(const float4*)&S[4096 + (ib + 3) * 64 + t4 * 4];
        float b0 = S[(t4 * 4 + 0) * 64 + j];
        float b1 = S[(t4 * 4 + 1) * 64 + j];
        float b2 = S[(t4 * 4 + 2) * 64 + j];
        float b3 = S[(t4 * 4 + 3) * 64 + j];
        a0 += f0.x * b0 + f0.y * b1 + f0.z * b2 + f0.w * b3;
        a1 += f1.x * b0 + f1.y * b1 + f1.z * b2 + f1.w * b3;
        a2 += f2.x * b0 + f2.y * b1 + f2.z * b2 + f2.w * b3;
        a3 += f3.x * b0 + f3.y * b1 + f3.z * b2 + f3.w * b3;
      }
      __half hv[4] = {__float2half(a0), __float2half(a1), __float2half(a2),
                      __float2half(a3)};
      *(uint2*)&bigWT[((k + 1) * 256 + h * 64 + j) * 128 + r0 + ib] =
          *(uint2*)hv;
    }
    if (k == 0) {
      #pragma unroll
      for (int u = 0; u < 8; ++u) {
        int idx = u * 256 + tid;
        int i = idx >> 6, jj = idx & 63;
        bigWT[(h * 64 + jj) * 128 + r0 + i] = __float2half(S[4096 + idx]);
      }
    }
  } else {
    #pragma unroll
    for (int u = 0; u < 4; ++u)
      ((float4*)S)[u * 256 + tid] =
          ((const float4*)(Bws + kh * 8192 + 4096))[u * 256 + tid];
    #pragma unroll
    for (int u = 0; u < 2; ++u)
      ((float4*)(S + 4096))[u * 256 + tid] =
          ((const float4*)(G + h * 2048))[u * 256 + tid];
    ((float4*)(S + 6144))[tid] = ((const float4*)emb)[tid];
    __syncthreads();
    int wv = tid >> 6;
    #pragma unroll
    for (int rg = 0; rg < 2; ++rg) {
      int g0 = wv * 8 + rg * 4;
      float a0 = 0.f, a1 = 0.f, a2 = 0.f, a3 = 0.f;
      #pragma unroll
      for (int t4 = 0; t4 < 16; ++t4) {
        float4 f0 = *(const float4*)&S[4096 + (g0 + 0) * 64 + t4 * 4];
        float4 f1 = *(const float4*)&S[4096 + (g0 + 1) * 64 + t4 * 4];
        float4 f2 = *(const float4*)&S[4096 + (g0 + 2) * 64 + t4 * 4];
        float4 f3 = *(const float4*)&S[4096 + (g0 + 3) * 64 + t4 * 4];
        float b0 = S[(t4 * 4 + 0) * 64 + j];
        float b1 = S[(t4 * 4 + 1) * 64 + j];
        float b2 = S[(t4 * 4 + 2) * 64 + j];
        float b3 = S[(t4 * 4 + 3) * 64 + j];
        a0 += f0.x * b0 + f0.y * b1 + f0.z * b2 + f0.w * b3;
        a1 += f1.x * b0 + f1.y * b1 + f1.z * b2 + f1.w * b3;
        a2 += f2.x * b0 + f2.y * b1 + f2.z * b2 + f2.w * b3;
        a3 += f3.x * b0 + f3.y * b1 + f3.z * b2 + f3.w * b3;
      }
      S[7168 + (g0 + 0) * 64 + j] = a0;
      S[7168 + (g0 + 1) * 64 + j] = a1;
      S[7168 + (g0 + 2) * 64 + j] = a2;
      S[7168 + (g0 + 3) * 64 + j] = a3;
    }
    __syncthreads();
    #pragma unroll
    for (int rg = 0; rg < 2; ++rg) {
      int e0 = wv * 8 + rg * 4;
      float a0 = 0.f, a1 = 0.f, a2 = 0.f, a3 = 0.f;
      #pragma unroll
      for (int t4 = 0; t4 < 8; ++t4) {
        float4 f0 = *(const float4*)&S[6144 + (e0 + 0) * 32 + t4 * 4];
        float4 f1 = *(const float4*)&S[6144 + (e0 + 1) * 32 + t4 * 4];
        float4 f2 = *(const float4*)&S[6144 + (e0 + 2) * 32 + t4 * 4];
        float4 f3 = *(const float4*)&S[6144 + (e0 + 3) * 32 + t4 * 4];
        float b0 = S[7168 + (t4 * 4 + 0) * 64 + j];
        float b1 = S[7168 + (t4 * 4 + 1) * 64 + j];
        float b2 = S[7168 + (t4 * 4 + 2) * 64 + j];
        float b3 = S[7168 + (t4 * 4 + 3) * 64 + j];
        a0 += f0.x * b0 + f0.y * b1 + f0.z * b2 + f0.w * b3;
        a1 += f1.x * b0 + f1.y * b1 + f1.z * b2 + f1.w * b3;
        a2 += f2.x * b0 + f2.y * b1 + f2.z * b2 + f2.w * b3;
        a3 += f3.x * b0 + f3.y * b1 + f3.z * b2 + f3.w * b3;
      }
      int base = k * 8192 + h * 2048;
      U16[base + (e0 + 0) * 64 + j] = __float2half(a0);
      U16[base + (e0 + 1) * 64 + j] = __float2half(a1);
      U16[base + (e0 + 2) * 64 + j] = __float2half(a2);
      U16[base + (e0 + 3) * 64 + j] = __float2half(a3);
    }
  }
}

// ---------------------------------------------------------------------------
// D3: block 0 = scan (256 threads, 40 nodes/lane); blocks 1..628 = MFMA gemm
// qall(fp16) = feat16 @ bigWT^T.  Tile 64 rows x 256 cols (region-uniform),
// grid (157 x 4) flattened; per-wave 16 rows, loop 16 n-subtiles, 4 acc VGPRs.
// ---------------------------------------------------------------------------
__global__ __launch_bounds__(256) void scan_gemm_kernel(
    const int* __restrict__ counts, int* __restrict__ starts,
    int* __restrict__ cursor, const __half* __restrict__ feat16,
    const __half* __restrict__ bigWT, __half* __restrict__ qall) {
  int bi = blockIdx.x;
  int tid = threadIdx.x;
  if (bi == 0) {
    __shared__ int lds[256];
    int base = tid * 40;
    int loc[40];
    int s = 0;
    #pragma unroll
    for (int u = 0; u < 40; ++u) {
      int i = base + u;
      int v = (i < N_NODES) ? counts[i] : 0;
      loc[u] = s;
      s += v;
    }
    lds[tid] = s;
    __syncthreads();
    int inc = s;
    for (int off = 1; off < 256; off <<= 1) {
      int y = (tid >= off) ? lds[tid - off] : 0;
      __syncthreads();
      inc += y;
      lds[tid] = inc;
      __syncthreads();
    }
    int excl = inc - s;
    #pragma unroll
    for (int u = 0; u < 40; ++u) {
      int i = base + u;
      if (i < N_NODES) {
        int v = excl + loc[u];
        starts[i] = v;
        cursor[i] = v;
      }
    }
    if (tid == 255) starts[N_NODES] = inc;
    return;
  }
  int gb = bi - 1;               // 0..627
  int bx = gb % 157, by = gb / 157;  // by = region 0..3
  int wv = tid >> 6, l = tid & 63;
  int m0 = bx * 64 + wv * 16;
  int n0 = by * 256;
  int lm = l & 15, lk = (l >> 4) * 8;
  int arow = m0 + lm;
  if (arow >= N_NODES) arow = N_NODES - 1;
  const _Float16* fp = (const _Float16*)feat16 + arow * 128 + lk;
  const _Float16* bp = (const _Float16*)bigWT + lk;
  half8 a[4];
  #pragma unroll
  for (int kt = 0; kt < 4; ++kt) a[kt] = *(const half8*)(fp + kt * 32);
  int mrow = m0 + (l >> 4) * 4;
  #pragma unroll
  for (int nt = 0; nt < 16; ++nt) {
    floatx4 acc = (floatx4){0.f, 0.f, 0.f, 0.f};
    #pragma unroll
    for (int kt = 0; kt < 4; ++kt) {
      half8 b = *(const half8*)(bp + (n0 + nt * 16 + lm) * 128 + kt * 32);
      acc = __builtin_amdgcn_mfma_f32_16x16x32_f16(a[kt], b, acc, 0, 0, 0);
    }
    int dd = nt * 16 + lm;  // col within region, 0..255
    int off = (by == 0) ? ((dd & 63) * 4 + (dd >> 6)) : (by * 256 + dd);
    #pragma unroll
    for (int r4 = 0; r4 < 4; ++r4) {
      int m = mrow + r4;
      if (m < N_NODES) qall[m * QREC + off] = __float2half(acc[r4]);
    }
  }
}

// ---------------------------------------------------------------------------
// D4: SCORE + FILL. One wave per edge e (ORIGINAL order -> src/dst/inter/widx
// loads sequential). h = lane>>4, c = lane&15. After scoring, lane 0 claims
// the CSR slot p = atomicAdd(cursor[dst]); scattered writes exsc/esrc.
// Max-free softmax (|score| <= ~15 -> exp cannot overflow fp32).
// ---------------------------------------------------------------------------
__device__ __forceinline__ float fast_tanh(float z) {
  float a = fabsf(z);
  float p = __expf(2.0f * a);
  float r = 1.0f - 2.0f / (p + 1.0f);
  return copysignf(r, z);
}

__device__ __forceinline__ float dpp_row_sum16(float v) {
  int x;
  x = __builtin_amdgcn_update_dpp(0, __float_as_int(v), 0x128, 0xf, 0xf, true);
  v += __int_as_float(x);
  x = __builtin_amdgcn_update_dpp(0, __float_as_int(v), 0x124, 0xf, 0xf, true);
  v += __int_as_float(x);
  x = __builtin_amdgcn_update_dpp(0, __float_as_int(v), 0x122, 0xf, 0xf, true);
  v += __int_as_float(x);
  x = __builtin_amdgcn_update_dpp(0, __float_as_int(v), 0x121, 0xf, 0xf, true);
  v += __int_as_float(x);
  return v;
}

union H4u { uint2 u; __half2 h[2]; };

__global__ __launch_bounds__(256) void score_fill_kernel(
    const int* __restrict__ src, const int* __restrict__ dst,
    const int* __restrict__ inter, const int* __restrict__ widx,
    const __half* __restrict__ qall, const __half* __restrict__ U16,
    const float* __restrict__ aout, int* __restrict__ cursor,
    float* __restrict__ exsc, int* __restrict__ esrc) {
  int tid = threadIdx.x;
  int wv = tid >> 6, lane = tid & 63;
  int h = lane >> 4, c = lane & 15;
  int e = blockIdx.x * 4 + wv;  // grid*4 == E exactly
  int s = src[e], t = dst[e];
  int it = inter[e * 4 + h];
  int wp = widx[e * 4 + h];
  int idx1 = wp & 31, idx2 = (wp >> 5) & 31, idx_ = (wp >> 10) & 31;
  H4u A, B, C, X, Y, Z;
  A.u = *(const uint2*)(qall + s * QREC + 256 + h * 64 + c * 4);
  B.u = *(const uint2*)(qall + it * QREC + 512 + h * 64 + c * 4);
  C.u = *(const uint2*)(qall + t * QREC + 768 + h * 64 + c * 4);
  X.u = *(const uint2*)(U16 + (h * 32 + idx1) * 64 + c * 4);
  Y.u = *(const uint2*)(U16 + 8192 + (h * 32 + idx2) * 64 + c * 4);
  Z.u = *(const uint2*)(U16 + 16384 + (h * 32 + idx_) * 64 + c * 4);
  const float4 a4 = *((const float4*)(aout + h * 64) + c);
  __half2 z0 = __hadd2(__hadd2(A.h[0], B.h[0]), __hadd2(C.h[0], X.h[0]));
  z0 = __hadd2(z0, __hadd2(Y.h[0], Z.h[0]));
  __half2 z1 = __hadd2(__hadd2(A.h[1], B.h[1]), __hadd2(C.h[1], X.h[1]));
  z1 = __hadd2(z1, __hadd2(Y.h[1], Z.h[1]));
  float2 f0 = __half22float2(z0);
  float2 f1 = __half22float2(z1);
  float t0 = fast_tanh(f0.x);
  float t1 = fast_tanh(f0.y);
  float t2 = fast_tanh(f1.x);
  float t3 = fast_tanh(f1.y);
  float v = t0 * a4.x + t1 * a4.y + t2 * a4.z + t3 * a4.w;
  v = dpp_row_sum16(v);
  int p = 0;
  if (lane == 0) p = atomicAdd(&cursor[t], 1);
  p = __shfl(p, 0);
  if (c == 0) exsc[p * 4 + h] = __expf(v);
  if (lane == 0) esrc[p] = s;
}

// ---------------------------------------------------------------------------
// D5: aggregation. Block per dst node; 4 waves stride CSR slots; lane = d.
// ---------------------------------------------------------------------------
__device__ __forceinline__ float4 h4_to_f4(uint2 u) {
  union { uint2 ui; __half2 h[2]; } cc;
  cc.ui = u;
  float2 a = __half22float2(cc.h[0]);
  float2 b = __half22float2(cc.h[1]);
  return make_float4(a.x, a.y, b.x, b.y);
}

__global__ __launch_bounds__(256) void agg_kernel(
    const int* __restrict__ starts, const int* __restrict__ esrc,
    const float* __restrict__ exsc, const __half* __restrict__ qall,
    float* __restrict__ out) {
  __shared__ float4 sm_num[4][64];
  __shared__ float4 sm_den[4];
  int tid = threadIdx.x;
  int w = tid >> 6, lane = tid & 63;
  int n = blockIdx.x;
  int b = starts[n], e_end = starts[n + 1];
  float4 num = make_float4(0.f, 0.f, 0.f, 0.f);
  float4 den = make_float4(0.f, 0.f, 0.f, 0.f);
  int i = b + w;
  float4 ex4 = make_float4(0.f, 0.f, 0.f, 0.f);
  uint2 hraw = {0, 0};
  if (i < e_end) {
    ex4 = *(const float4*)(exsc + i * 4);
    int s = esrc[i];
    hraw = *(const uint2*)(qall + s * QREC + lane * 4);
  }
  while (i < e_end) {
    int inext = i + 4;
    float4 ex4n = make_float4(0.f, 0.f, 0.f, 0.f);
    uint2 hrawn = {0, 0};
    if (inext < e_end) {
      ex4n = *(const float4*)(exsc + inext * 4);
      int sn = esrc[inext];
      hrawn = *(const uint2*)(qall + sn * QREC + lane * 4);
    }
    float4 hv = h4_to_f4(hraw);  // h[d=lane][head 0..3]
    num.x += ex4.x * hv.x;
    num.y += ex4.y * hv.y;
    num.z += ex4.z * hv.z;
    num.w += ex4.w * hv.w;
    den.x += ex4.x; den.y += ex4.y; den.z += ex4.z; den.w += ex4.w;
    i = inext;
    ex4 = ex4n;
    hraw = hrawn;
  }
  sm_num[w][lane] = num;
  if (lane == 0) sm_den[w] = den;
  __syncthreads();
  if (tid < 64) {
    float4 n0 = sm_num[0][tid], n1 = sm_num[1][tid];
    float4 n2 = sm_num[2][tid], n3 = sm_num[3][tid];
    float4 d0 = sm_den[0], d1 = sm_den[1], d2 = sm_den[2], d3 = sm_den[3];
    float4 ns = make_float4(n0.x + n1.x + n2.x + n3.x, n0.y + n1.y + n2.y + n3.y,
                            n0.z + n1.z + n2.z + n3.z, n0.w + n1.w + n2.w + n3.w);
    float4 ds = make_float4(d0.x + d1.x + d2.x + d3.x, d0.y + d1.y + d2.y + d3.y,
                            d0.z + d1.z + d2.z + d3.z, d0.w + d1.w + d2.w + d3.w);
    float r = 0.f;
    if (e_end > b)
      r = 0.25f * (ns.x / ds.x + ns.y / ds.y + ns.z / ds.z + ns.w / ds.w);
    out[n * 64 + tid] = r;
  }
}

// ---------------------------------------------------------------------------
extern "C" void kernel_launch(void* const* d_in, const int* in_sizes, int n_in,
                              void* d_out, int out_size, void* d_ws,
                              size_t ws_size, hipStream_t stream) {
  const float* feat = (const float*)d_in[0];
  const float* loc = (const float*)d_in[1];
  const int* src = (const int*)d_in[2];
  const int* dst = (const int*)d_in[3];
  const int* inter = (const int*)d_in[4];
  const float* Wfc = (const float*)d_in[5];
  const float* emb = (const float*)d_in[6];
  const float* G = (const float*)d_in[7];
  const float* fc1 = (const float*)d_in[8];
  const float* fc2 = (const float*)d_in[9];
  const float* fc3 = (const float*)d_in[10];
  const float* fcc = (const float*)d_in[11];
  const float* aout = (const float*)d_in[12];
  const float* bnd = (const float*)d_in[13];
  float* out = (float*)d_out;

  __half* qall = (__half*)d_ws;                    // N*1024 halfs (20.48 MB)
  __half* bigWT = qall + N_NODES * QREC;           // 1024*128 halfs
  __half* U16 = bigWT + 1024 * 128;                // 3*4*2048 halfs
  __half* feat16 = U16 + 3 * H * 2048;             // N*128 halfs
  float* Bws = (float*)(feat16 + N_NODES * 128);   // 12*8192 f32
  float4* pos4 = (float4*)(Bws + 12 * 8192);       // N float4
  float* exsc = (float*)(pos4 + N_NODES);          // E*4 f32
  int* widx = (int*)(exsc + E_EDGES * 4);          // E*4 ints
  int* counts = widx + E_EDGES * 4;                // N
  int* starts = counts + N_NODES;                  // N+1
  int* cursor = starts + N_NODES + 1;              // N
  int* esrc = cursor + N_NODES;                    // E

  prep_pre1_cvt_kernel<<<1302, 256, 0, stream>>>(fc1, fc2, fc3, fcc, Bws, loc,
                                                 pos4, counts, feat, feat16);
  pre2_dist_kernel<<<60 + E_EDGES * 4 / 256, 256, 0, stream>>>(
      Wfc, G, emb, Bws, bigWT, U16, src, dst, inter, pos4, bnd, counts, widx);
  scan_gemm_kernel<<<1 + 157 * 4, 256, 0, stream>>>(counts, starts, cursor,
                                                    feat16, bigWT, qall);
  score_fill_kernel<<<E_EDGES / 4, 256, 0, stream>>>(
      src, dst, inter, widx, qall, U16, aout, cursor, exsc, esrc);
  agg_kernel<<<N_NODES, 256, 0, stream>>>(starts, esrc, exsc, qall, out);
}

// Round 11
// 214.648 us; speedup vs baseline: 1.1663x; 1.0224x over previous
//
#include <hip/hip_runtime.h>
#include <hip/hip_fp16.h>
#include <math.h>

#define N_NODES 10000
#define E_EDGES 160000
#define DMODEL 64
#define H 4
#define NBOUND 31
// qall record per node (fp16, 1024 halves):
//  [0:256)    h  d-major: offset d*4 + head   (one 8B load = all 4 heads at d)
//  [256:512)  q1: 256 + head*64 + d
//  [512:768)  q2: 512 + head*64 + d
//  [768:1024) q3: 768 + head*64 + d
#define QREC 1024

typedef _Float16 half8 __attribute__((ext_vector_type(8)));
typedef float floatx4 __attribute__((ext_vector_type(4)));

// ---------------------------------------------------------------------------
// D1: blocks 0..11 pre1 (B[kh] = fck @ F -> Bws); 12..51 prep (pos4+counts);
//     52..1301 cvt feat -> feat16.
// ---------------------------------------------------------------------------
__global__ __launch_bounds__(256) void prep_pre1_cvt_kernel(
    const float* __restrict__ fc1, const float* __restrict__ fc2,
    const float* __restrict__ fc3, const float* __restrict__ fcc,
    float* __restrict__ Bws, const float* __restrict__ pos,
    float4* __restrict__ pos4, int* __restrict__ counts,
    const float* __restrict__ feat, __half* __restrict__ feat16) {
  __shared__ __align__(16) float S[12288];  // [0:8192) fck, [8192:12288) F
  int bi = blockIdx.x;
  int tid = threadIdx.x;
  if (bi >= 52) {
    int t = (bi - 52) * 256 + tid;  // 1250*256 == N*128/4 exactly
    float4 v = *(const float4*)(feat + t * 4);
    union { uint2 u; __half2 h[2]; } st;
    st.h[0] = __floats2half2_rn(v.x, v.y);
    st.h[1] = __floats2half2_rn(v.z, v.w);
    *(uint2*)&feat16[t * 4] = st.u;
    return;
  }
  if (bi >= 12) {
    int n = (bi - 12) * 256 + tid;
    if (n < N_NODES) {
      counts[n] = 0;
      pos4[n] = make_float4(pos[n * 3], pos[n * 3 + 1], pos[n * 3 + 2], 0.f);
    }
    return;
  }
  int kh = bi;
  int k = kh >> 2, h = kh & 3;
  const float* fck = (k == 0) ? fc1 : (k == 1) ? fc2 : fc3;
  fck += h * 128 * 64;
  const float* F = fcc + h * 192 * 64 + k * 64 * 64;
  #pragma unroll
  for (int u = 0; u < 8; ++u)
    ((float4*)S)[u * 256 + tid] = ((const float4*)fck)[u * 256 + tid];
  #pragma unroll
  for (int u = 0; u < 4; ++u)
    ((float4*)(S + 8192))[u * 256 + tid] = ((const float4*)F)[u * 256 + tid];
  __syncthreads();
  int j = tid & 63, ig = tid >> 6;
  #pragma unroll
  for (int rg = 0; rg < 8; ++rg) {
    int i0 = ig * 32 + rg * 4;
    float a0 = 0.f, a1 = 0.f, a2 = 0.f, a3 = 0.f;
    #pragma unroll
    for (int t4 = 0; t4 < 16; ++t4) {
      float4 f0 = *(const float4*)&S[(i0 + 0) * 64 + t4 * 4];
      float4 f1 = *(const float4*)&S[(i0 + 1) * 64 + t4 * 4];
      float4 f2 = *(const float4*)&S[(i0 + 2) * 64 + t4 * 4];
      float4 f3 = *(const float4*)&S[(i0 + 3) * 64 + t4 * 4];
      float b0 = S[8192 + (t4 * 4 + 0) * 64 + j];
      float b1 = S[8192 + (t4 * 4 + 1) * 64 + j];
      float b2 = S[8192 + (t4 * 4 + 2) * 64 + j];
      float b3 = S[8192 + (t4 * 4 + 3) * 64 + j];
      a0 += f0.x * b0 + f0.y * b1 + f0.z * b2 + f0.w * b3;
      a1 += f1.x * b0 + f1.y * b1 + f1.z * b2 + f1.w * b3;
      a2 += f2.x * b0 + f2.y * b1 + f2.z * b2 + f2.w * b3;
      a3 += f3.x * b0 + f3.y * b1 + f3.z * b2 + f3.w * b3;
    }
    Bws[kh * 8192 + (i0 + 0) * 64 + j] = a0;
    Bws[kh * 8192 + (i0 + 1) * 64 + j] = a1;
    Bws[kh * 8192 + (i0 + 2) * 64 + j] = a2;
    Bws[kh * 8192 + (i0 + 3) * 64 + j] = a3;
  }
}

// ---------------------------------------------------------------------------
__device__ __forceinline__ int didx(const float* __restrict__ bnd2, float d) {
  int g = (int)(d * 10.0f);
  g = (g < 0) ? 0 : ((g > 31) ? 31 : g);
  g += (bnd2[g + 1] < d) ? 1 : 0;
  g -= (bnd2[g] >= d) ? 1 : 0;
  return g;
}

// ---------------------------------------------------------------------------
// D2: blocks 0..59 pre2 (WC->bigWT fp16, U->U16 fp16); 60.. dist/count.
// ---------------------------------------------------------------------------
__global__ __launch_bounds__(256) void pre2_dist_kernel(
    const float* __restrict__ Wfc, const float* __restrict__ G,
    const float* __restrict__ emb, const float* __restrict__ Bws,
    __half* __restrict__ bigWT, __half* __restrict__ U16,
    const int* __restrict__ src, const int* __restrict__ dst,
    const int* __restrict__ inter, const float4* __restrict__ pos4,
    const float* __restrict__ boundaries, int* __restrict__ counts,
    int* __restrict__ widx) {
  __shared__ __align__(16) float S[9216];
  int bi = blockIdx.x;
  int tid = threadIdx.x;
  if (bi >= 60) {
    if (tid < NBOUND) S[tid + 1] = boundaries[tid];
    if (tid == NBOUND) { S[0] = -INFINITY; S[32] = INFINITY; }
    __syncthreads();
    int g = (bi - 60) * 256 + tid;  // (e,h); 2500 blocks x 256 == E*4
    int e = g >> 2, h = g & 3;
    int s = src[e], t = dst[e];
    int it = inter[g];
    float4 ps = pos4[s], pt = pos4[t], pi = pos4[it];
    float dx = pt.x - ps.x, dy = pt.y - ps.y, dz = pt.z - ps.z;
    float dist1 = sqrtf(dx * dx + dy * dy + dz * dz);
    float ax = pt.x - pi.x, ay = pt.y - pi.y, az = pt.z - pi.z;
    float dist2 = sqrtf(ax * ax + ay * ay + az * az);
    float bx = ps.x - pi.x, by = ps.y - pi.y, bz = ps.z - pi.z;
    float dist_ = sqrtf(bx * bx + by * by + bz * bz);
    int idx1 = didx(S, dist1);
    int idx2 = didx(S, dist2);
    int idx_ = didx(S, dist_);
    widx[g] = idx1 | (idx2 << 5) | (idx_ << 10);
    if (h == 0) atomicAdd(&counts[t], 1);
    return;
  }
  int kh = bi / 5, role = bi % 5;
  int k = kh >> 2, h = kh & 3;
  int j = tid & 63;
  if (role < 4) {
    int r0 = role * 32;
    #pragma unroll
    for (int u = 0; u < 4; ++u)
      ((float4*)S)[u * 256 + tid] = ((const float4*)(Bws + kh * 8192))[u * 256 + tid];
    #pragma unroll
    for (int u = 0; u < 2; ++u) {
      int fi = u * 256 + tid;
      int i = fi >> 4, c4 = fi & 15;
      ((float4*)(S + 4096))[fi] =
          ((const float4*)(Wfc + (r0 + i) * 256 + h * 64))[c4];
    }
    __syncthreads();
    int ig = tid >> 6;
    int i0 = ig * 8;
    #pragma unroll
    for (int g4 = 0; g4 < 2; ++g4) {
      int ib = i0 + g4 * 4;
      float a0 = 0.f, a1 = 0.f, a2 = 0.f, a3 = 0.f;
      #pragma unroll
      for (int t4 = 0; t4 < 16; ++t4) {
        float4 f0 = *(const float4*)&S[4096 + (ib + 0) * 64 + t4 * 4];
        float4 f1 = *(const float4*)&S[4096 + (ib + 1) * 64 + t4 * 4];
        float4 f2 = *(const float4*)&S[4096 + (ib + 2) * 64 + t4 * 4];
        float4 f3 = *(const float4*)&S[4096 + (ib + 3) * 64 + t4 * 4];
        float b0 = S[(t4 * 4 + 0) * 64 + j];
        float b1 = S[(t4 * 4 + 1) * 64 + j];
        float b2 = S[(t4 * 4 + 2) * 64 + j];
        float b3 = S[(t4 * 4 + 3) * 64 + j];
        a0 += f0.x * b0 + f0.y * b1 + f0.z * b2 + f0.w * b3;
        a1 += f1.x * b0 + f1.y * b1 + f1.z * b2 + f1.w * b3;
        a2 += f2.x * b0 + f2.y * b1 + f2.z * b2 + f2.w * b3;
        a3 += f3.x * b0 + f3.y * b1 + f3.z * b2 + f3.w * b3;
      }
      __half hv[4] = {__float2half(a0), __float2half(a1), __float2half(a2),
                      __float2half(a3)};
      *(uint2*)&bigWT[((k + 1) * 256 + h * 64 + j) * 128 + r0 + ib] =
          *(uint2*)hv;
    }
    if (k == 0) {
      #pragma unroll
      for (int u = 0; u < 8; ++u) {
        int idx = u * 256 + tid;
        int i = idx >> 6, jj = idx & 63;
        bigWT[(h * 64 + jj) * 128 + r0 + i] = __float2half(S[4096 + idx]);
      }
    }
  } else {
    #pragma unroll
    for (int u = 0; u < 4; ++u)
      ((float4*)S)[u * 256 + tid] =
          ((const float4*)(Bws + kh * 8192 + 4096))[u * 256 + tid];
    #pragma unroll
    for (int u = 0; u < 2; ++u)
      ((float4*)(S + 4096))[u * 256 + tid] =
          ((const float4*)(G + h * 2048))[u * 256 + tid];
    ((float4*)(S + 6144))[tid] = ((const float4*)emb)[tid];
    __syncthreads();
    int wv = tid >> 6;
    #pragma unroll
    for (int rg = 0; rg < 2; ++rg) {
      int g0 = wv * 8 + rg * 4;
      float a0 = 0.f, a1 = 0.f, a2 = 0.f, a3 = 0.f;
      #pragma unroll
      for (int t4 = 0; t4 < 16; ++t4) {
        float4 f0 = *(const float4*)&S[4096 + (g0 + 0) * 64 + t4 * 4];
        float4 f1 = *(const float4*)&S[4096 + (g0 + 1) * 64 + t4 * 4];
        float4 f2 = *(const float4*)&S[4096 + (g0 + 2) * 64 + t4 * 4];
        float4 f3 = *(const float4*)&S[4096 + (g0 + 3) * 64 + t4 * 4];
        float b0 = S[(t4 * 4 + 0) * 64 + j];
        float b1 = S[(t4 * 4 + 1) * 64 + j];
        float b2 = S[(t4 * 4 + 2) * 64 + j];
        float b3 = S[(t4 * 4 + 3) * 64 + j];
        a0 += f0.x * b0 + f0.y * b1 + f0.z * b2 + f0.w * b3;
        a1 += f1.x * b0 + f1.y * b1 + f1.z * b2 + f1.w * b3;
        a2 += f2.x * b0 + f2.y * b1 + f2.z * b2 + f2.w * b3;
        a3 += f3.x * b0 + f3.y * b1 + f3.z * b2 + f3.w * b3;
      }
      S[7168 + (g0 + 0) * 64 + j] = a0;
      S[7168 + (g0 + 1) * 64 + j] = a1;
      S[7168 + (g0 + 2) * 64 + j] = a2;
      S[7168 + (g0 + 3) * 64 + j] = a3;
    }
    __syncthreads();
    #pragma unroll
    for (int rg = 0; rg < 2; ++rg) {
      int e0 = wv * 8 + rg * 4;
      float a0 = 0.f, a1 = 0.f, a2 = 0.f, a3 = 0.f;
      #pragma unroll
      for (int t4 = 0; t4 < 8; ++t4) {
        float4 f0 = *(const float4*)&S[6144 + (e0 + 0) * 32 + t4 * 4];
        float4 f1 = *(const float4*)&S[6144 + (e0 + 1) * 32 + t4 * 4];
        float4 f2 = *(const float4*)&S[6144 + (e0 + 2) * 32 + t4 * 4];
        float4 f3 = *(const float4*)&S[6144 + (e0 + 3) * 32 + t4 * 4];
        float b0 = S[7168 + (t4 * 4 + 0) * 64 + j];
        float b1 = S[7168 + (t4 * 4 + 1) * 64 + j];
        float b2 = S[7168 + (t4 * 4 + 2) * 64 + j];
        float b3 = S[7168 + (t4 * 4 + 3) * 64 + j];
        a0 += f0.x * b0 + f0.y * b1 + f0.z * b2 + f0.w * b3;
        a1 += f1.x * b0 + f1.y * b1 + f1.z * b2 + f1.w * b3;
        a2 += f2.x * b0 + f2.y * b1 + f2.z * b2 + f2.w * b3;
        a3 += f3.x * b0 + f3.y * b1 + f3.z * b2 + f3.w * b3;
      }
      int base = k * 8192 + h * 2048;
      U16[base + (e0 + 0) * 64 + j] = __float2half(a0);
      U16[base + (e0 + 1) * 64 + j] = __float2half(a1);
      U16[base + (e0 + 2) * 64 + j] = __float2half(a2);
      U16[base + (e0 + 3) * 64 + j] = __float2half(a3);
    }
  }
}

// ---------------------------------------------------------------------------
// D3: block 0 = scan; blocks 1..628 = MFMA gemm (64 x 256 region tiles).
// ---------------------------------------------------------------------------
__global__ __launch_bounds__(256) void scan_gemm_kernel(
    const int* __restrict__ counts, int* __restrict__ starts,
    int* __restrict__ cursor, const __half* __restrict__ feat16,
    const __half* __restrict__ bigWT, __half* __restrict__ qall) {
  int bi = blockIdx.x;
  int tid = threadIdx.x;
  if (bi == 0) {
    __shared__ int lds[256];
    int base = tid * 40;
    int loc[40];
    int s = 0;
    #pragma unroll
    for (int u = 0; u < 40; ++u) {
      int i = base + u;
      int v = (i < N_NODES) ? counts[i] : 0;
      loc[u] = s;
      s += v;
    }
    lds[tid] = s;
    __syncthreads();
    int inc = s;
    for (int off = 1; off < 256; off <<= 1) {
      int y = (tid >= off) ? lds[tid - off] : 0;
      __syncthreads();
      inc += y;
      lds[tid] = inc;
      __syncthreads();
    }
    int excl = inc - s;
    #pragma unroll
    for (int u = 0; u < 40; ++u) {
      int i = base + u;
      if (i < N_NODES) {
        int v = excl + loc[u];
        starts[i] = v;
        cursor[i] = v;
      }
    }
    if (tid == 255) starts[N_NODES] = inc;
    return;
  }
  int gb = bi - 1;               // 0..627
  int bx = gb % 157, by = gb / 157;  // by = region 0..3
  int wv = tid >> 6, l = tid & 63;
  int m0 = bx * 64 + wv * 16;
  int n0 = by * 256;
  int lm = l & 15, lk = (l >> 4) * 8;
  int arow = m0 + lm;
  if (arow >= N_NODES) arow = N_NODES - 1;
  const _Float16* fp = (const _Float16*)feat16 + arow * 128 + lk;
  const _Float16* bp = (const _Float16*)bigWT + lk;
  half8 a[4];
  #pragma unroll
  for (int kt = 0; kt < 4; ++kt) a[kt] = *(const half8*)(fp + kt * 32);
  int mrow = m0 + (l >> 4) * 4;
  #pragma unroll
  for (int nt = 0; nt < 16; ++nt) {
    floatx4 acc = (floatx4){0.f, 0.f, 0.f, 0.f};
    #pragma unroll
    for (int kt = 0; kt < 4; ++kt) {
      half8 b = *(const half8*)(bp + (n0 + nt * 16 + lm) * 128 + kt * 32);
      acc = __builtin_amdgcn_mfma_f32_16x16x32_f16(a[kt], b, acc, 0, 0, 0);
    }
    int dd = nt * 16 + lm;  // col within region, 0..255
    int off = (by == 0) ? ((dd & 63) * 4 + (dd >> 6)) : (by * 256 + dd);
    #pragma unroll
    for (int r4 = 0; r4 < 4; ++r4) {
      int m = mrow + r4;
      if (m < N_NODES) qall[m * QREC + off] = __float2half(acc[r4]);
    }
  }
}

// ---------------------------------------------------------------------------
// D4: SCORE + FILL. One wave per edge e (original order). h=lane>>4, c=lane&15.
// tanh-dot identity: sum_d a_d*tanh(z_d) = sum_d a_d - 2*sum_d a_d/(e^{2z}+1)
// (signed form, no abs/copysign: e^{-inf}=0 -> -1; e^{+inf}=inf -> rcp=0 -> +1)
// Max-free softmax (|score| <= ~15 -> exp cannot overflow fp32).
// ---------------------------------------------------------------------------
__device__ __forceinline__ float dpp_row_sum16(float v) {
  int x;
  x = __builtin_amdgcn_update_dpp(0, __float_as_int(v), 0x128, 0xf, 0xf, true);
  v += __int_as_float(x);
  x = __builtin_amdgcn_update_dpp(0, __float_as_int(v), 0x124, 0xf, 0xf, true);
  v += __int_as_float(x);
  x = __builtin_amdgcn_update_dpp(0, __float_as_int(v), 0x122, 0xf, 0xf, true);
  v += __int_as_float(x);
  x = __builtin_amdgcn_update_dpp(0, __float_as_int(v), 0x121, 0xf, 0xf, true);
  v += __int_as_float(x);
  return v;
}

union H4u { uint2 u; __half2 h[2]; };

__global__ __launch_bounds__(256) void score_fill_kernel(
    const int* __restrict__ src, const int* __restrict__ dst,
    const int* __restrict__ inter, const int* __restrict__ widx,
    const __half* __restrict__ qall, const __half* __restrict__ U16,
    const float* __restrict__ aout, int* __restrict__ cursor,
    float* __restrict__ exsc, int* __restrict__ esrc) {
  int tid = threadIdx.x;
  int wv = tid >> 6, lane = tid & 63;
  int h = lane >> 4, c = lane & 15;
  int e = blockIdx.x * 4 + wv;  // grid*4 == E exactly
  int s = src[e], t = dst[e];
  int it = inter[e * 4 + h];
  int wp = widx[e * 4 + h];
  int idx1 = wp & 31, idx2 = (wp >> 5) & 31, idx_ = (wp >> 10) & 31;
  H4u A, B, C, X, Y, Z;
  A.u = *(const uint2*)(qall + s * QREC + 256 + h * 64 + c * 4);
  B.u = *(const uint2*)(qall + it * QREC + 512 + h * 64 + c * 4);
  C.u = *(const uint2*)(qall + t * QREC + 768 + h * 64 + c * 4);
  X.u = *(const uint2*)(U16 + (h * 32 + idx1) * 64 + c * 4);
  Y.u = *(const uint2*)(U16 + 8192 + (h * 32 + idx2) * 64 + c * 4);
  Z.u = *(const uint2*)(U16 + 16384 + (h * 32 + idx_) * 64 + c * 4);
  const float4 a4 = *((const float4*)(aout + h * 64) + c);
  __half2 z0 = __hadd2(__hadd2(A.h[0], B.h[0]), __hadd2(C.h[0], X.h[0]));
  z0 = __hadd2(z0, __hadd2(Y.h[0], Z.h[0]));
  __half2 z1 = __hadd2(__hadd2(A.h[1], B.h[1]), __hadd2(C.h[1], X.h[1]));
  z1 = __hadd2(z1, __hadd2(Y.h[1], Z.h[1]));
  float2 f0 = __half22float2(z0);
  float2 f1 = __half22float2(z1);
  const float K = 2.885390082f;  // 2*log2(e)
  float p0 = __builtin_amdgcn_exp2f(f0.x * K);
  float p1 = __builtin_amdgcn_exp2f(f0.y * K);
  float p2 = __builtin_amdgcn_exp2f(f1.x * K);
  float p3 = __builtin_amdgcn_exp2f(f1.y * K);
  float r0 = __builtin_amdgcn_rcpf(p0 + 1.0f);
  float r1 = __builtin_amdgcn_rcpf(p1 + 1.0f);
  float r2 = __builtin_amdgcn_rcpf(p2 + 1.0f);
  float r3 = __builtin_amdgcn_rcpf(p3 + 1.0f);
  float dot = a4.x * r0;
  dot = fmaf(a4.y, r1, dot);
  dot = fmaf(a4.z, r2, dot);
  dot = fmaf(a4.w, r3, dot);
  float asum = (a4.x + a4.y) + (a4.z + a4.w);
  float v = fmaf(-2.0f, dot, asum);
  v = dpp_row_sum16(v);
  int p = 0;
  if (lane == 0) p = atomicAdd(&cursor[t], 1);
  p = __shfl(p, 0);
  if (c == 0) exsc[p * 4 + h] = __expf(v);
  if (lane == 0) esrc[p] = s;
}

// ---------------------------------------------------------------------------
// D5: aggregation. Block per dst node; 4 waves stride CSR slots; lane = d.
// Unroll-2 + prefetch-2: up to 4 outstanding h-gathers per wave. OOB slots
// load as zero (ex=0 -> zero contribution), so consumes need no guards.
// ---------------------------------------------------------------------------
__device__ __forceinline__ float4 h4_to_f4(uint2 u) {
  union { uint2 ui; __half2 h[2]; } cc;
  cc.ui = u;
  float2 a = __half22float2(cc.h[0]);
  float2 b = __half22float2(cc.h[1]);
  return make_float4(a.x, a.y, b.x, b.y);
}

__global__ __launch_bounds__(256) void agg_kernel(
    const int* __restrict__ starts, const int* __restrict__ esrc,
    const float* __restrict__ exsc, const __half* __restrict__ qall,
    float* __restrict__ out) {
  __shared__ float4 sm_num[4][64];
  __shared__ float4 sm_den[4];
  int tid = threadIdx.x;
  int w = tid >> 6, lane = tid & 63;
  int n = blockIdx.x;
  int b = starts[n], e_end = starts[n + 1];
  float4 num = make_float4(0.f, 0.f, 0.f, 0.f);
  float4 den = make_float4(0.f, 0.f, 0.f, 0.f);
  int i = b + w;
  float4 exA = make_float4(0.f, 0.f, 0.f, 0.f);
  float4 exB = make_float4(0.f, 0.f, 0.f, 0.f);
  uint2 hA = {0, 0}, hB = {0, 0};
  if (i < e_end) {
    exA = *(const float4*)(exsc + i * 4);
    hA = *(const uint2*)(qall + esrc[i] * QREC + lane * 4);
  }
  if (i + 4 < e_end) {
    exB = *(const float4*)(exsc + (i + 4) * 4);
    hB = *(const uint2*)(qall + esrc[i + 4] * QREC + lane * 4);
  }
  while (i < e_end) {
    int i2 = i + 8, i3 = i + 12;
    float4 exC = make_float4(0.f, 0.f, 0.f, 0.f);
    float4 exD = make_float4(0.f, 0.f, 0.f, 0.f);
    uint2 hC = {0, 0}, hD = {0, 0};
    if (i2 < e_end) {
      exC = *(const float4*)(exsc + i2 * 4);
      hC = *(const uint2*)(qall + esrc[i2] * QREC + lane * 4);
    }
    if (i3 < e_end) {
      exD = *(const float4*)(exsc + i3 * 4);
      hD = *(const uint2*)(qall + esrc[i3] * QREC + lane * 4);
    }
    float4 hvA = h4_to_f4(hA);  // h[d=lane][head 0..3]
    num.x += exA.x * hvA.x;
    num.y += exA.y * hvA.y;
    num.z += exA.z * hvA.z;
    num.w += exA.w * hvA.w;
    den.x += exA.x; den.y += exA.y; den.z += exA.z; den.w += exA.w;
    float4 hvB = h4_to_f4(hB);
    num.x += exB.x * hvB.x;
    num.y += exB.y * hvB.y;
    num.z += exB.z * hvB.z;
    num.w += exB.w * hvB.w;
    den.x += exB.x; den.y += exB.y; den.z += exB.z; den.w += exB.w;
    i = i2;
    exA = exC; hA = hC;
    exB = exD; hB = hD;
  }
  sm_num[w][lane] = num;
  if (lane == 0) sm_den[w] = den;
  __syncthreads();
  if (tid < 64) {
    float4 n0 = sm_num[0][tid], n1 = sm_num[1][tid];
    float4 n2 = sm_num[2][tid], n3 = sm_num[3][tid];
    float4 d0 = sm_den[0], d1 = sm_den[1], d2 = sm_den[2], d3 = sm_den[3];
    float4 ns = make_float4(n0.x + n1.x + n2.x + n3.x, n0.y + n1.y + n2.y + n3.y,
                            n0.z + n1.z + n2.z + n3.z, n0.w + n1.w + n2.w + n3.w);
    float4 ds = make_float4(d0.x + d1.x + d2.x + d3.x, d0.y + d1.y + d2.y + d3.y,
                            d0.z + d1.z + d2.z + d3.z, d0.w + d1.w + d2.w + d3.w);
    float r = 0.f;
    if (e_end > b)
      r = 0.25f * (ns.x / ds.x + ns.y / ds.y + ns.z / ds.z + ns.w / ds.w);
    out[n * 64 + tid] = r;
  }
}

// ---------------------------------------------------------------------------
extern "C" void kernel_launch(void* const* d_in, const int* in_sizes, int n_in,
                              void* d_out, int out_size, void* d_ws,
                              size_t ws_size, hipStream_t stream) {
  const float* feat = (const float*)d_in[0];
  const float* loc = (const float*)d_in[1];
  const int* src = (const int*)d_in[2];
  const int* dst = (const int*)d_in[3];
  const int* inter = (const int*)d_in[4];
  const float* Wfc = (const float*)d_in[5];
  const float* emb = (const float*)d_in[6];
  const float* G = (const float*)d_in[7];
  const float* fc1 = (const float*)d_in[8];
  const float* fc2 = (const float*)d_in[9];
  const float* fc3 = (const float*)d_in[10];
  const float* fcc = (const float*)d_in[11];
  const float* aout = (const float*)d_in[12];
  const float* bnd = (const float*)d_in[13];
  float* out = (float*)d_out;

  __half* qall = (__half*)d_ws;                    // N*1024 halfs (20.48 MB)
  __half* bigWT = qall + N_NODES * QREC;           // 1024*128 halfs
  __half* U16 = bigWT + 1024 * 128;                // 3*4*2048 halfs
  __half* feat16 = U16 + 3 * H * 2048;             // N*128 halfs
  float* Bws = (float*)(feat16 + N_NODES * 128);   // 12*8192 f32
  float4* pos4 = (float4*)(Bws + 12 * 8192);       // N float4
  float* exsc = (float*)(pos4 + N_NODES);          // E*4 f32
  int* widx = (int*)(exsc + E_EDGES * 4);          // E*4 ints
  int* counts = widx + E_EDGES * 4;                // N
  int* starts = counts + N_NODES;                  // N+1
  int* cursor = starts + N_NODES + 1;              // N
  int* esrc = cursor + N_NODES;                    // E

  prep_pre1_cvt_kernel<<<1302, 256, 0, stream>>>(fc1, fc2, fc3, fcc, Bws, loc,
                                                 pos4, counts, feat, feat16);
  pre2_dist_kernel<<<60 + E_EDGES * 4 / 256, 256, 0, stream>>>(
      Wfc, G, emb, Bws, bigWT, U16, src, dst, inter, pos4, bnd, counts, widx);
  scan_gemm_kernel<<<1 + 157 * 4, 256, 0, stream>>>(counts, starts, cursor,
                                                    feat16, bigWT, qall);
  score_fill_kernel<<<E_EDGES / 4, 256, 0, stream>>>(
      src, dst, inter, widx, qall, U16, aout, cursor, exsc, esrc);
  agg_kernel<<<N_NODES, 256, 0, stream>>>(starts, esrc, exsc, qall, out);
}

// Round 12
// 209.718 us; speedup vs baseline: 1.1938x; 1.0235x over previous
//
#include <hip/hip_runtime.h>
#include <hip/hip_fp16.h>
#include <math.h>

#define N_NODES 10000
#define E_EDGES 160000
#define DMODEL 64
#define H 4
#define NBOUND 31
// qall record per node (fp16, 1024 halves):
//  [0:256)    h  d-major: offset d*4 + head   (one 8B load = all 4 heads at d)
//  [256:512)  q1: 256 + head*64 + d
//  [512:768)  q2: 512 + head*64 + d
//  [768:1024) q3: 768 + head*64 + d
#define QREC 1024

typedef _Float16 half8 __attribute__((ext_vector_type(8)));
typedef float floatx4 __attribute__((ext_vector_type(4)));

// ---------------------------------------------------------------------------
// D1: blocks 0..11 pre1 (B[kh] = fck @ F -> Bws); 12..51 prep (pos4+counts);
//     52..1301 cvt feat -> feat16.
// ---------------------------------------------------------------------------
__global__ __launch_bounds__(256) void prep_pre1_cvt_kernel(
    const float* __restrict__ fc1, const float* __restrict__ fc2,
    const float* __restrict__ fc3, const float* __restrict__ fcc,
    float* __restrict__ Bws, const float* __restrict__ pos,
    float4* __restrict__ pos4, int* __restrict__ counts,
    const float* __restrict__ feat, __half* __restrict__ feat16) {
  __shared__ __align__(16) float S[12288];  // [0:8192) fck, [8192:12288) F
  int bi = blockIdx.x;
  int tid = threadIdx.x;
  if (bi >= 52) {
    int t = (bi - 52) * 256 + tid;  // 1250*256 == N*128/4 exactly
    float4 v = *(const float4*)(feat + t * 4);
    union { uint2 u; __half2 h[2]; } st;
    st.h[0] = __floats2half2_rn(v.x, v.y);
    st.h[1] = __floats2half2_rn(v.z, v.w);
    *(uint2*)&feat16[t * 4] = st.u;
    return;
  }
  if (bi >= 12) {
    int n = (bi - 12) * 256 + tid;
    if (n < N_NODES) {
      counts[n] = 0;
      pos4[n] = make_float4(pos[n * 3], pos[n * 3 + 1], pos[n * 3 + 2], 0.f);
    }
    return;
  }
  int kh = bi;
  int k = kh >> 2, h = kh & 3;
  const float* fck = (k == 0) ? fc1 : (k == 1) ? fc2 : fc3;
  fck += h * 128 * 64;
  const float* F = fcc + h * 192 * 64 + k * 64 * 64;
  #pragma unroll
  for (int u = 0; u < 8; ++u)
    ((float4*)S)[u * 256 + tid] = ((const float4*)fck)[u * 256 + tid];
  #pragma unroll
  for (int u = 0; u < 4; ++u)
    ((float4*)(S + 8192))[u * 256 + tid] = ((const float4*)F)[u * 256 + tid];
  __syncthreads();
  int j = tid & 63, ig = tid >> 6;
  #pragma unroll
  for (int rg = 0; rg < 8; ++rg) {
    int i0 = ig * 32 + rg * 4;
    float a0 = 0.f, a1 = 0.f, a2 = 0.f, a3 = 0.f;
    #pragma unroll
    for (int t4 = 0; t4 < 16; ++t4) {
      float4 f0 = *(const float4*)&S[(i0 + 0) * 64 + t4 * 4];
      float4 f1 = *(const float4*)&S[(i0 + 1) * 64 + t4 * 4];
      float4 f2 = *(const float4*)&S[(i0 + 2) * 64 + t4 * 4];
      float4 f3 = *(const float4*)&S[(i0 + 3) * 64 + t4 * 4];
      float b0 = S[8192 + (t4 * 4 + 0) * 64 + j];
      float b1 = S[8192 + (t4 * 4 + 1) * 64 + j];
      float b2 = S[8192 + (t4 * 4 + 2) * 64 + j];
      float b3 = S[8192 + (t4 * 4 + 3) * 64 + j];
      a0 += f0.x * b0 + f0.y * b1 + f0.z * b2 + f0.w * b3;
      a1 += f1.x * b0 + f1.y * b1 + f1.z * b2 + f1.w * b3;
      a2 += f2.x * b0 + f2.y * b1 + f2.z * b2 + f2.w * b3;
      a3 += f3.x * b0 + f3.y * b1 + f3.z * b2 + f3.w * b3;
    }
    Bws[kh * 8192 + (i0 + 0) * 64 + j] = a0;
    Bws[kh * 8192 + (i0 + 1) * 64 + j] = a1;
    Bws[kh * 8192 + (i0 + 2) * 64 + j] = a2;
    Bws[kh * 8192 + (i0 + 3) * 64 + j] = a3;
  }
}

// ---------------------------------------------------------------------------
__device__ __forceinline__ int didx(const float* __restrict__ bnd2, float d) {
  int g = (int)(d * 10.0f);
  g = (g < 0) ? 0 : ((g > 31) ? 31 : g);
  g += (bnd2[g + 1] < d) ? 1 : 0;
  g -= (bnd2[g] >= d) ? 1 : 0;
  return g;
}

// ---------------------------------------------------------------------------
// D2: blocks 0..59 pre2 (WC->bigWT fp16, U->U16 fp16); 60..1309 dist/count
//     (2 (e,h) pairs per lane).
// ---------------------------------------------------------------------------
__device__ __forceinline__ void dist_one(
    const float* __restrict__ S, const int* __restrict__ src,
    const int* __restrict__ dst, const int* __restrict__ inter,
    const float4* __restrict__ pos4, int* __restrict__ counts,
    int* __restrict__ widx, int g) {
  int e = g >> 2, h = g & 3;
  int s = src[e], t = dst[e];
  int it = inter[g];
  float4 ps = pos4[s], pt = pos4[t], pi = pos4[it];
  float dx = pt.x - ps.x, dy = pt.y - ps.y, dz = pt.z - ps.z;
  float dist1 = sqrtf(dx * dx + dy * dy + dz * dz);
  float ax = pt.x - pi.x, ay = pt.y - pi.y, az = pt.z - pi.z;
  float dist2 = sqrtf(ax * ax + ay * ay + az * az);
  float bx = ps.x - pi.x, by = ps.y - pi.y, bz = ps.z - pi.z;
  float dist_ = sqrtf(bx * bx + by * by + bz * bz);
  int idx1 = didx(S, dist1);
  int idx2 = didx(S, dist2);
  int idx_ = didx(S, dist_);
  widx[g] = idx1 | (idx2 << 5) | (idx_ << 10);
  if (h == 0) atomicAdd(&counts[t], 1);
}

__global__ __launch_bounds__(256) void pre2_dist_kernel(
    const float* __restrict__ Wfc, const float* __restrict__ G,
    const float* __restrict__ emb, const float* __restrict__ Bws,
    __half* __restrict__ bigWT, __half* __restrict__ U16,
    const int* __restrict__ src, const int* __restrict__ dst,
    const int* __restrict__ inter, const float4* __restrict__ pos4,
    const float* __restrict__ boundaries, int* __restrict__ counts,
    int* __restrict__ widx) {
  __shared__ __align__(16) float S[9216];
  int bi = blockIdx.x;
  int tid = threadIdx.x;
  if (bi >= 60) {
    if (tid < NBOUND) S[tid + 1] = boundaries[tid];
    if (tid == NBOUND) { S[0] = -INFINITY; S[32] = INFINITY; }
    __syncthreads();
    int g0 = (bi - 60) * 512 + tid;  // 1250 blocks x 512 == E*4 exactly
    dist_one(S, src, dst, inter, pos4, counts, widx, g0);
    dist_one(S, src, dst, inter, pos4, counts, widx, g0 + 256);
    return;
  }
  int kh = bi / 5, role = bi % 5;
  int k = kh >> 2, h = kh & 3;
  int j = tid & 63;
  if (role < 4) {
    int r0 = role * 32;
    #pragma unroll
    for (int u = 0; u < 4; ++u)
      ((float4*)S)[u * 256 + tid] = ((const float4*)(Bws + kh * 8192))[u * 256 + tid];
    #pragma unroll
    for (int u = 0; u < 2; ++u) {
      int fi = u * 256 + tid;
      int i = fi >> 4, c4 = fi & 15;
      ((float4*)(S + 4096))[fi] =
          ((const float4*)(Wfc + (r0 + i) * 256 + h * 64))[c4];
    }
    __syncthreads();
    int ig = tid >> 6;
    int i0 = ig * 8;
    #pragma unroll
    for (int g4 = 0; g4 < 2; ++g4) {
      int ib = i0 + g4 * 4;
      float a0 = 0.f, a1 = 0.f, a2 = 0.f, a3 = 0.f;
      #pragma unroll
      for (int t4 = 0; t4 < 16; ++t4) {
        float4 f0 = *(const float4*)&S[4096 + (ib + 0) * 64 + t4 * 4];
        float4 f1 = *(const float4*)&S[4096 + (ib + 1) * 64 + t4 * 4];
        float4 f2 = *(const float4*)&S[4096 + (ib + 2) * 64 + t4 * 4];
        float4 f3 = *(const float4*)&S[4096 + (ib + 3) * 64 + t4 * 4];
        float b0 = S[(t4 * 4 + 0) * 64 + j];
        float b1 = S[(t4 * 4 + 1) * 64 + j];
        float b2 = S[(t4 * 4 + 2) * 64 + j];
        float b3 = S[(t4 * 4 + 3) * 64 + j];
        a0 += f0.x * b0 + f0.y * b1 + f0.z * b2 + f0.w * b3;
        a1 += f1.x * b0 + f1.y * b1 + f1.z * b2 + f1.w * b3;
        a2 += f2.x * b0 + f2.y * b1 + f2.z * b2 + f2.w * b3;
        a3 += f3.x * b0 + f3.y * b1 + f3.z * b2 + f3.w * b3;
      }
      __half hv[4] = {__float2half(a0), __float2half(a1), __float2half(a2),
                      __float2half(a3)};
      *(uint2*)&bigWT[((k + 1) * 256 + h * 64 + j) * 128 + r0 + ib] =
          *(uint2*)hv;
    }
    if (k == 0) {
      #pragma unroll
      for (int u = 0; u < 8; ++u) {
        int idx = u * 256 + tid;
        int i = idx >> 6, jj = idx & 63;
        bigWT[(h * 64 + jj) * 128 + r0 + i] = __float2half(S[4096 + idx]);
      }
    }
  } else {
    #pragma unroll
    for (int u = 0; u < 4; ++u)
      ((float4*)S)[u * 256 + tid] =
          ((const float4*)(Bws + kh * 8192 + 4096))[u * 256 + tid];
    #pragma unroll
    for (int u = 0; u < 2; ++u)
      ((float4*)(S + 4096))[u * 256 + tid] =
          ((const float4*)(G + h * 2048))[u * 256 + tid];
    ((float4*)(S + 6144))[tid] = ((const float4*)emb)[tid];
    __syncthreads();
    int wv = tid >> 6;
    #pragma unroll
    for (int rg = 0; rg < 2; ++rg) {
      int g0 = wv * 8 + rg * 4;
      float a0 = 0.f, a1 = 0.f, a2 = 0.f, a3 = 0.f;
      #pragma unroll
      for (int t4 = 0; t4 < 16; ++t4) {
        float4 f0 = *(const float4*)&S[4096 + (g0 + 0) * 64 + t4 * 4];
        float4 f1 = *(const float4*)&S[4096 + (g0 + 1) * 64 + t4 * 4];
        float4 f2 = *(const float4*)&S[4096 + (g0 + 2) * 64 + t4 * 4];
        float4 f3 = *(const float4*)&S[4096 + (g0 + 3) * 64 + t4 * 4];
        float b0 = S[(t4 * 4 + 0) * 64 + j];
        float b1 = S[(t4 * 4 + 1) * 64 + j];
        float b2 = S[(t4 * 4 + 2) * 64 + j];
        float b3 = S[(t4 * 4 + 3) * 64 + j];
        a0 += f0.x * b0 + f0.y * b1 + f0.z * b2 + f0.w * b3;
        a1 += f1.x * b0 + f1.y * b1 + f1.z * b2 + f1.w * b3;
        a2 += f2.x * b0 + f2.y * b1 + f2.z * b2 + f2.w * b3;
        a3 += f3.x * b0 + f3.y * b1 + f3.z * b2 + f3.w * b3;
      }
      S[7168 + (g0 + 0) * 64 + j] = a0;
      S[7168 + (g0 + 1) * 64 + j] = a1;
      S[7168 + (g0 + 2) * 64 + j] = a2;
      S[7168 + (g0 + 3) * 64 + j] = a3;
    }
    __syncthreads();
    #pragma unroll
    for (int rg = 0; rg < 2; ++rg) {
      int e0 = wv * 8 + rg * 4;
      float a0 = 0.f, a1 = 0.f, a2 = 0.f, a3 = 0.f;
      #pragma unroll
      for (int t4 = 0; t4 < 8; ++t4) {
        float4 f0 = *(const float4*)&S[6144 + (e0 + 0) * 32 + t4 * 4];
        float4 f1 = *(const float4*)&S[6144 + (e0 + 1) * 32 + t4 * 4];
        float4 f2 = *(const float4*)&S[6144 + (e0 + 2) * 32 + t4 * 4];
        float4 f3 = *(const float4*)&S[6144 + (e0 + 3) * 32 + t4 * 4];
        float b0 = S[7168 + (t4 * 4 + 0) * 64 + j];
        float b1 = S[7168 + (t4 * 4 + 1) * 64 + j];
        float b2 = S[7168 + (t4 * 4 + 2) * 64 + j];
        float b3 = S[7168 + (t4 * 4 + 3) * 64 + j];
        a0 += f0.x * b0 + f0.y * b1 + f0.z * b2 + f0.w * b3;
        a1 += f1.x * b0 + f1.y * b1 + f1.z * b2 + f1.w * b3;
        a2 += f2.x * b0 + f2.y * b1 + f2.z * b2 + f2.w * b3;
        a3 += f3.x * b0 + f3.y * b1 + f3.z * b2 + f3.w * b3;
      }
      int base = k * 8192 + h * 2048;
      U16[base + (e0 + 0) * 64 + j] = __float2half(a0);
      U16[base + (e0 + 1) * 64 + j] = __float2half(a1);
      U16[base + (e0 + 2) * 64 + j] = __float2half(a2);
      U16[base + (e0 + 3) * 64 + j] = __float2half(a3);
    }
  }
}

// ---------------------------------------------------------------------------
// D3: block 0 = scan; blocks 1..628 = MFMA gemm (64 x 256 region tiles).
// Epilogue: acc -> LDS (region-0 permutation applied at LDS-write), barrier,
// then 8 x 16B vector stores per lane (was 64 x 2B scalar stores).
// ---------------------------------------------------------------------------
#define EROW 264  // LDS row stride in halves (pad to de-phase banks)

__global__ __launch_bounds__(256) void scan_gemm_kernel(
    const int* __restrict__ counts, int* __restrict__ starts,
    int* __restrict__ cursor, const __half* __restrict__ feat16,
    const __half* __restrict__ bigWT, __half* __restrict__ qall) {
  int bi = blockIdx.x;
  int tid = threadIdx.x;
  if (bi == 0) {
    __shared__ int lds[256];
    int base = tid * 40;
    int loc[40];
    int s = 0;
    #pragma unroll
    for (int u = 0; u < 40; ++u) {
      int i = base + u;
      int v = (i < N_NODES) ? counts[i] : 0;
      loc[u] = s;
      s += v;
    }
    lds[tid] = s;
    __syncthreads();
    int inc = s;
    for (int off = 1; off < 256; off <<= 1) {
      int y = (tid >= off) ? lds[tid - off] : 0;
      __syncthreads();
      inc += y;
      lds[tid] = inc;
      __syncthreads();
    }
    int excl = inc - s;
    #pragma unroll
    for (int u = 0; u < 40; ++u) {
      int i = base + u;
      if (i < N_NODES) {
        int v = excl + loc[u];
        starts[i] = v;
        cursor[i] = v;
      }
    }
    if (tid == 255) starts[N_NODES] = inc;
    return;
  }
  __shared__ __align__(16) __half Esm[4][16][EROW];
  int gb = bi - 1;               // 0..627
  int bx = gb % 157, by = gb / 157;  // by = region 0..3
  int wv = tid >> 6, l = tid & 63;
  int m0 = bx * 64 + wv * 16;
  int n0 = by * 256;
  int lm = l & 15, lk = (l >> 4) * 8;
  int arow = m0 + lm;
  if (arow >= N_NODES) arow = N_NODES - 1;
  const _Float16* fp = (const _Float16*)feat16 + arow * 128 + lk;
  const _Float16* bp = (const _Float16*)bigWT + lk;
  half8 a[4];
  #pragma unroll
  for (int kt = 0; kt < 4; ++kt) a[kt] = *(const half8*)(fp + kt * 32);
  #pragma unroll
  for (int nt = 0; nt < 16; ++nt) {
    floatx4 acc = (floatx4){0.f, 0.f, 0.f, 0.f};
    #pragma unroll
    for (int kt = 0; kt < 4; ++kt) {
      half8 b = *(const half8*)(bp + (n0 + nt * 16 + lm) * 128 + kt * 32);
      acc = __builtin_amdgcn_mfma_f32_16x16x32_f16(a[kt], b, acc, 0, 0, 0);
    }
    int dd = nt * 16 + lm;  // col within region, 0..255
    int o = (by == 0) ? ((dd & 63) * 4 + (dd >> 6)) : dd;
    #pragma unroll
    for (int r4 = 0; r4 < 4; ++r4) {
      Esm[wv][(l >> 4) * 4 + r4][o] = __float2half(acc[r4]);
    }
  }
  __syncthreads();
  int row = l >> 2;           // 0..15
  int j0 = (l & 3) * 64;      // 0,64,128,192
  int m = m0 + row;
  if (m < N_NODES) {
    #pragma unroll
    for (int u = 0; u < 8; ++u) {
      uint4 v = *(const uint4*)&Esm[wv][row][j0 + u * 8];
      *(uint4*)&qall[m * QREC + by * 256 + j0 + u * 8] = v;
    }
  }
}

// ---------------------------------------------------------------------------
// D4: SCORE + FILL. One wave per TWO edges (doubled memory-level parallelism;
// one-shot waves were concurrency-limited at ~59us across 3 VALU loads).
// h=lane>>4, c=lane&15. tanh-dot identity (signed): sum a*tanh(z) =
// sum a - 2*sum a/(e^{2z}+1). Max-free softmax (|score| <= ~15).
// ---------------------------------------------------------------------------
__device__ __forceinline__ float dpp_row_sum16(float v) {
  int x;
  x = __builtin_amdgcn_update_dpp(0, __float_as_int(v), 0x128, 0xf, 0xf, true);
  v += __int_as_float(x);
  x = __builtin_amdgcn_update_dpp(0, __float_as_int(v), 0x124, 0xf, 0xf, true);
  v += __int_as_float(x);
  x = __builtin_amdgcn_update_dpp(0, __float_as_int(v), 0x122, 0xf, 0xf, true);
  v += __int_as_float(x);
  x = __builtin_amdgcn_update_dpp(0, __float_as_int(v), 0x121, 0xf, 0xf, true);
  v += __int_as_float(x);
  return v;
}

union H4u { uint2 u; __half2 h[2]; };

__device__ __forceinline__ float tanh_dot(H4u A, H4u B, H4u C, H4u X, H4u Y,
                                          H4u Z, float4 a4) {
  __half2 z0 = __hadd2(__hadd2(A.h[0], B.h[0]), __hadd2(C.h[0], X.h[0]));
  z0 = __hadd2(z0, __hadd2(Y.h[0], Z.h[0]));
  __half2 z1 = __hadd2(__hadd2(A.h[1], B.h[1]), __hadd2(C.h[1], X.h[1]));
  z1 = __hadd2(z1, __hadd2(Y.h[1], Z.h[1]));
  float2 f0 = __half22float2(z0);
  float2 f1 = __half22float2(z1);
  const float K = 2.885390082f;  // 2*log2(e)
  float p0 = __builtin_amdgcn_exp2f(f0.x * K);
  float p1 = __builtin_amdgcn_exp2f(f0.y * K);
  float p2 = __builtin_amdgcn_exp2f(f1.x * K);
  float p3 = __builtin_amdgcn_exp2f(f1.y * K);
  float r0 = __builtin_amdgcn_rcpf(p0 + 1.0f);
  float r1 = __builtin_amdgcn_rcpf(p1 + 1.0f);
  float r2 = __builtin_amdgcn_rcpf(p2 + 1.0f);
  float r3 = __builtin_amdgcn_rcpf(p3 + 1.0f);
  float dot = a4.x * r0;
  dot = fmaf(a4.y, r1, dot);
  dot = fmaf(a4.z, r2, dot);
  dot = fmaf(a4.w, r3, dot);
  float asum = (a4.x + a4.y) + (a4.z + a4.w);
  return fmaf(-2.0f, dot, asum);
}

__global__ __launch_bounds__(256) void score_fill_kernel(
    const int* __restrict__ src, const int* __restrict__ dst,
    const int* __restrict__ inter, const int* __restrict__ widx,
    const __half* __restrict__ qall, const __half* __restrict__ U16,
    const float* __restrict__ aout, int* __restrict__ cursor,
    float* __restrict__ exsc, int* __restrict__ esrc) {
  int tid = threadIdx.x;
  int wv = tid >> 6, lane = tid & 63;
  int h = lane >> 4, c = lane & 15;
  int e0 = blockIdx.x * 8 + wv * 2;  // grid*8 == E exactly
  int e1 = e0 + 1;
  int s0 = src[e0], t0 = dst[e0];
  int s1 = src[e1], t1 = dst[e1];
  int it0 = inter[e0 * 4 + h], it1 = inter[e1 * 4 + h];
  int wp0 = widx[e0 * 4 + h], wp1 = widx[e1 * 4 + h];
  int i10 = wp0 & 31, i20 = (wp0 >> 5) & 31, i_0 = (wp0 >> 10) & 31;
  int i11 = wp1 & 31, i21 = (wp1 >> 5) & 31, i_1 = (wp1 >> 10) & 31;
  H4u A0, B0, C0, X0, Y0, Z0, A1, B1, C1, X1, Y1, Z1;
  A0.u = *(const uint2*)(qall + s0 * QREC + 256 + h * 64 + c * 4);
  A1.u = *(const uint2*)(qall + s1 * QREC + 256 + h * 64 + c * 4);
  B0.u = *(const uint2*)(qall + it0 * QREC + 512 + h * 64 + c * 4);
  B1.u = *(const uint2*)(qall + it1 * QREC + 512 + h * 64 + c * 4);
  C0.u = *(const uint2*)(qall + t0 * QREC + 768 + h * 64 + c * 4);
  C1.u = *(const uint2*)(qall + t1 * QREC + 768 + h * 64 + c * 4);
  X0.u = *(const uint2*)(U16 + (h * 32 + i10) * 64 + c * 4);
  X1.u = *(const uint2*)(U16 + (h * 32 + i11) * 64 + c * 4);
  Y0.u = *(const uint2*)(U16 + 8192 + (h * 32 + i20) * 64 + c * 4);
  Y1.u = *(const uint2*)(U16 + 8192 + (h * 32 + i21) * 64 + c * 4);
  Z0.u = *(const uint2*)(U16 + 16384 + (h * 32 + i_0) * 64 + c * 4);
  Z1.u = *(const uint2*)(U16 + 16384 + (h * 32 + i_1) * 64 + c * 4);
  const float4 a4 = *((const float4*)(aout + h * 64) + c);
  float v0 = tanh_dot(A0, B0, C0, X0, Y0, Z0, a4);
  float v1 = tanh_dot(A1, B1, C1, X1, Y1, Z1, a4);
  v0 = dpp_row_sum16(v0);
  v1 = dpp_row_sum16(v1);
  int p0 = 0, p1 = 0;
  if (lane == 0) {
    p0 = atomicAdd(&cursor[t0], 1);
    p1 = atomicAdd(&cursor[t1], 1);
  }
  p0 = __shfl(p0, 0);
  p1 = __shfl(p1, 0);
  if (c == 0) {
    exsc[p0 * 4 + h] = __expf(v0);
    exsc[p1 * 4 + h] = __expf(v1);
  }
  if (lane == 0) {
    esrc[p0] = s0;
    esrc[p1] = s1;
  }
}

// ---------------------------------------------------------------------------
// D5: aggregation. Block per dst node; 4 waves stride CSR slots; lane = d.
// Flat unroll-4: all 8 loads issued before any consume (8 outstanding).
// Zero-init both buffers so skipped slots contribute exactly 0.
// ---------------------------------------------------------------------------
__device__ __forceinline__ float4 h4_to_f4(uint2 u) {
  union { uint2 ui; __half2 h[2]; } cc;
  cc.ui = u;
  float2 a = __half22float2(cc.h[0]);
  float2 b = __half22float2(cc.h[1]);
  return make_float4(a.x, a.y, b.x, b.y);
}

__global__ __launch_bounds__(256) void agg_kernel(
    const int* __restrict__ starts, const int* __restrict__ esrc,
    const float* __restrict__ exsc, const __half* __restrict__ qall,
    float* __restrict__ out) {
  __shared__ float4 sm_num[4][64];
  __shared__ float4 sm_den[4];
  int tid = threadIdx.x;
  int w = tid >> 6, lane = tid & 63;
  int n = blockIdx.x;
  int b = starts[n], e_end = starts[n + 1];
  float4 num = make_float4(0.f, 0.f, 0.f, 0.f);
  float4 den = make_float4(0.f, 0.f, 0.f, 0.f);
  int i = b + w;
  while (i < e_end) {
    float4 ex[4];
    uint2 hr[4];
    #pragma unroll
    for (int u = 0; u < 4; ++u) {
      ex[u] = make_float4(0.f, 0.f, 0.f, 0.f);
      hr[u] = make_uint2(0, 0);
      int idx = i + u * 4;
      if (idx < e_end) {
        ex[u] = *(const float4*)(exsc + idx * 4);
        hr[u] = *(const uint2*)(qall + esrc[idx] * QREC + lane * 4);
      }
    }
    #pragma unroll
    for (int u = 0; u < 4; ++u) {
      float4 hv = h4_to_f4(hr[u]);  // h[d=lane][head 0..3]
      num.x += ex[u].x * hv.x;
      num.y += ex[u].y * hv.y;
      num.z += ex[u].z * hv.z;
      num.w += ex[u].w * hv.w;
      den.x += ex[u].x; den.y += ex[u].y; den.z += ex[u].z; den.w += ex[u].w;
    }
    i += 16;
  }
  sm_num[w][lane] = num;
  if (lane == 0) sm_den[w] = den;
  __syncthreads();
  if (tid < 64) {
    float4 n0 = sm_num[0][tid], n1 = sm_num[1][tid];
    float4 n2 = sm_num[2][tid], n3 = sm_num[3][tid];
    float4 d0 = sm_den[0], d1 = sm_den[1], d2 = sm_den[2], d3 = sm_den[3];
    float4 ns = make_float4(n0.x + n1.x + n2.x + n3.x, n0.y + n1.y + n2.y + n3.y,
                            n0.z + n1.z + n2.z + n3.z, n0.w + n1.w + n2.w + n3.w);
    float4 ds = make_float4(d0.x + d1.x + d2.x + d3.x, d0.y + d1.y + d2.y + d3.y,
                            d0.z + d1.z + d2.z + d3.z, d0.w + d1.w + d2.w + d3.w);
    float r = 0.f;
    if (e_end > b)
      r = 0.25f * (ns.x / ds.x + ns.y / ds.y + ns.z / ds.z + ns.w / ds.w);
    out[n * 64 + tid] = r;
  }
}

// ---------------------------------------------------------------------------
extern "C" void kernel_launch(void* const* d_in, const int* in_sizes, int n_in,
                              void* d_out, int out_size, void* d_ws,
                              size_t ws_size, hipStream_t stream) {
  const float* feat = (const float*)d_in[0];
  const float* loc = (const float*)d_in[1];
  const int* src = (const int*)d_in[2];
  const int* dst = (const int*)d_in[3];
  const int* inter = (const int*)d_in[4];
  const float* Wfc = (const float*)d_in[5];
  const float* emb = (const float*)d_in[6];
  const float* G = (const float*)d_in[7];
  const float* fc1 = (const float*)d_in[8];
  const float* fc2 = (const float*)d_in[9];
  const float* fc3 = (const float*)d_in[10];
  const float* fcc = (const float*)d_in[11];
  const float* aout = (const float*)d_in[12];
  const float* bnd = (const float*)d_in[13];
  float* out = (float*)d_out;

  __half* qall = (__half*)d_ws;                    // N*1024 halfs (20.48 MB)
  __half* bigWT = qall + N_NODES * QREC;           // 1024*128 halfs
  __half* U16 = bigWT + 1024 * 128;                // 3*4*2048 halfs
  __half* feat16 = U16 + 3 * H * 2048;             // N*128 halfs
  float* Bws = (float*)(feat16 + N_NODES * 128);   // 12*8192 f32
  float4* pos4 = (float4*)(Bws + 12 * 8192);       // N float4
  float* exsc = (float*)(pos4 + N_NODES);          // E*4 f32
  int* widx = (int*)(exsc + E_EDGES * 4);          // E*4 ints
  int* counts = widx + E_EDGES * 4;                // N
  int* starts = counts + N_NODES;                  // N+1
  int* cursor = starts + N_NODES + 1;              // N
  int* esrc = cursor + N_NODES;                    // E

  prep_pre1_cvt_kernel<<<1302, 256, 0, stream>>>(fc1, fc2, fc3, fcc, Bws, loc,
                                                 pos4, counts, feat, feat16);
  pre2_dist_kernel<<<60 + 1250, 256, 0, stream>>>(
      Wfc, G, emb, Bws, bigWT, U16, src, dst, inter, pos4, bnd, counts, widx);
  scan_gemm_kernel<<<1 + 157 * 4, 256, 0, stream>>>(counts, starts, cursor,
                                                    feat16, bigWT, qall);
  score_fill_kernel<<<E_EDGES / 8, 256, 0, stream>>>(
      src, dst, inter, widx, qall, U16, aout, cursor, exsc, esrc);
  agg_kernel<<<N_NODES, 256, 0, stream>>>(starts, esrc, exsc, qall, out);
}